// Round 1
// baseline (1949.685 us; speedup 1.0000x reference)
//
#include <hip/hip_runtime.h>

#define N_NODES 100000
#define N_EDGES 1600000
// dims: in 256, hid 128, out 40

// ---------------- degree / dinv ----------------
__global__ __launch_bounds__(256) void deg_count_kernel(
    const int* __restrict__ dst, float* __restrict__ deg, int E) {
  int i = blockIdx.x * blockDim.x + threadIdx.x;
  int stride = gridDim.x * blockDim.x;
  for (; i < E; i += stride) atomicAdd(&deg[dst[i]], 1.0f);
}

__global__ __launch_bounds__(256) void dinv_kernel(float* __restrict__ deg, int n) {
  int i = blockIdx.x * blockDim.x + threadIdx.x;
  if (i < n) deg[i] = rsqrtf(1.0f + deg[i]);
}

// ---------------- GEMM1: [M,256] @ [256,128] -> [M,128] ----------------
// tile 64 rows x 128 cols, BK=32, 256 threads, 8x4 acc per thread
__global__ __launch_bounds__(256) void gemm1_kernel(
    const float* __restrict__ A, const float* __restrict__ B,
    float* __restrict__ C, int M) {
  __shared__ float As[32][68];   // transposed: As[k][row], stride 68 to break conflicts
  __shared__ float Bs[32][128];
  const int tid = threadIdx.x;
  const int row0 = blockIdx.x * 64;
  const int tc = tid & 31;   // 32 col-threads * 4 cols = 128
  const int tr = tid >> 5;   // 8 row-threads * 8 rows = 64
  float acc[8][4];
#pragma unroll
  for (int r = 0; r < 8; ++r)
#pragma unroll
    for (int c = 0; c < 4; ++c) acc[r][c] = 0.f;

  for (int kt = 0; kt < 256; kt += 32) {
#pragma unroll
    for (int l = 0; l < 2; ++l) {
      int s = tid + l * 256;       // 0..511 float4 slots (64 rows x 8)
      int row = s >> 3;
      int kq = s & 7;
      int rg = min(row0 + row, M - 1);
      float4 v = *(const float4*)(A + (size_t)rg * 256 + kt + kq * 4);
      As[kq * 4 + 0][row] = v.x;
      As[kq * 4 + 1][row] = v.y;
      As[kq * 4 + 2][row] = v.z;
      As[kq * 4 + 3][row] = v.w;
    }
#pragma unroll
    for (int l = 0; l < 4; ++l) {
      int s = tid + l * 256;       // 0..1023 float4 slots (32 k x 32)
      int k = s >> 5;
      int cq = s & 31;
      *(float4*)(&Bs[k][cq * 4]) = *(const float4*)(B + (size_t)(kt + k) * 128 + cq * 4);
    }
    __syncthreads();
#pragma unroll
    for (int k = 0; k < 32; ++k) {
      float4 b = *(const float4*)(&Bs[k][tc * 4]);
      float4 a0 = *(const float4*)(&As[k][tr * 8]);
      float4 a1 = *(const float4*)(&As[k][tr * 8 + 4]);
      float av[8] = {a0.x, a0.y, a0.z, a0.w, a1.x, a1.y, a1.z, a1.w};
      float bv[4] = {b.x, b.y, b.z, b.w};
#pragma unroll
      for (int r = 0; r < 8; ++r)
#pragma unroll
        for (int c = 0; c < 4; ++c) acc[r][c] += av[r] * bv[c];
    }
    __syncthreads();
  }
#pragma unroll
  for (int r = 0; r < 8; ++r) {
    int row = row0 + tr * 8 + r;
    if (row < M) {
      float4 v = make_float4(acc[r][0], acc[r][1], acc[r][2], acc[r][3]);
      *(float4*)(C + (size_t)row * 128 + tc * 4) = v;
    }
  }
}

// ---------------- scatter layer 1: 128 ch, one wave per edge ----------------
__global__ __launch_bounds__(256) void scatter1_kernel(
    const int* __restrict__ src, const int* __restrict__ dst,
    const float* __restrict__ dinv, const float* __restrict__ h,
    float* __restrict__ agg, int E) {
  int gw = (blockIdx.x * blockDim.x + threadIdx.x) >> 6;
  int lane = threadIdx.x & 63;
  if (gw >= E) return;
  int s = src[gw], d = dst[gw];
  float norm = dinv[s] * dinv[d];
  const float2 v = *(const float2*)(h + (size_t)s * 128 + lane * 2);
  atomicAdd(agg + (size_t)d * 128 + lane * 2, v.x * norm);
  atomicAdd(agg + (size_t)d * 128 + lane * 2 + 1, v.y * norm);
}

// ---------------- finalize layer1: agg = relu(agg + h*dinv^2 + b) ----------------
__global__ __launch_bounds__(256) void finalize1_kernel(
    float* __restrict__ agg, const float* __restrict__ h,
    const float* __restrict__ dinv, const float* __restrict__ b, int nq) {
  int i = blockIdx.x * blockDim.x + threadIdx.x;  // float4 index over N*128/4
  if (i >= nq) return;
  int node = i >> 5;          // 32 float4 per row
  int cq = (i & 31) * 4;
  float di = dinv[node];
  float sl = di * di;
  float4 a = *(float4*)(agg + (size_t)i * 4);
  float4 hv = *(const float4*)(h + (size_t)i * 4);
  float4 bv = *(const float4*)(b + cq);
  a.x = fmaxf(a.x + hv.x * sl + bv.x, 0.f);
  a.y = fmaxf(a.y + hv.y * sl + bv.y, 0.f);
  a.z = fmaxf(a.z + hv.z * sl + bv.z, 0.f);
  a.w = fmaxf(a.w + hv.w * sl + bv.w, 0.f);
  *(float4*)(agg + (size_t)i * 4) = a;
}

// ---------------- GEMM2: [M,128] @ [128,40] -> [M,40] ----------------
// tile 128 rows x 40 cols, 256 threads, 4 rows x 5 cols per thread
__global__ __launch_bounds__(256) void gemm2_kernel(
    const float* __restrict__ A, const float* __restrict__ B,
    float* __restrict__ C, int M) {
  __shared__ float As[32][132];   // transposed
  __shared__ float Bs[128][40];   // all of W2
  const int tid = threadIdx.x;
  const int row0 = blockIdx.x * 128;
#pragma unroll
  for (int l = 0; l < 5; ++l) {
    int s = tid + l * 256;        // 1280 float4 slots
    *(float4*)((float*)Bs + (size_t)s * 4) = *(const float4*)(B + (size_t)s * 4);
  }
  const int tc = tid & 7;    // cols tc + 8j, j<5
  const int tr = tid >> 3;   // rows tr*4..+3
  float acc[4][5];
#pragma unroll
  for (int r = 0; r < 4; ++r)
#pragma unroll
    for (int j = 0; j < 5; ++j) acc[r][j] = 0.f;

  for (int kt = 0; kt < 128; kt += 32) {
#pragma unroll
    for (int l = 0; l < 4; ++l) {
      int s = tid + l * 256;      // 1024 float4 slots (128 rows x 8)
      int row = s >> 3;
      int kq = s & 7;
      int rg = min(row0 + row, M - 1);
      float4 v = *(const float4*)(A + (size_t)rg * 128 + kt + kq * 4);
      As[kq * 4 + 0][row] = v.x;
      As[kq * 4 + 1][row] = v.y;
      As[kq * 4 + 2][row] = v.z;
      As[kq * 4 + 3][row] = v.w;
    }
    __syncthreads();
#pragma unroll
    for (int k = 0; k < 32; ++k) {
      float4 a = *(const float4*)(&As[k][tr * 4]);
      float av[4] = {a.x, a.y, a.z, a.w};
#pragma unroll
      for (int j = 0; j < 5; ++j) {
        float bv = Bs[kt + k][tc + 8 * j];
#pragma unroll
        for (int r = 0; r < 4; ++r) acc[r][j] += av[r] * bv;
      }
    }
    __syncthreads();
  }
#pragma unroll
  for (int r = 0; r < 4; ++r) {
    int row = row0 + tr * 4 + r;
    if (row < M) {
#pragma unroll
      for (int j = 0; j < 5; ++j) C[(size_t)row * 40 + tc + 8 * j] = acc[r][j];
    }
  }
}

// ---------------- out init: out = h2*dinv^2 + b2 ----------------
__global__ __launch_bounds__(256) void outinit_kernel(
    float* __restrict__ out, const float* __restrict__ h2,
    const float* __restrict__ dinv, const float* __restrict__ b, int total) {
  int i = blockIdx.x * blockDim.x + threadIdx.x;
  if (i >= total) return;
  int node = i / 40;
  int c = i - node * 40;
  float di = dinv[node];
  out[i] = h2[i] * di * di + b[c];
}

// ---------------- scatter layer 2: 40 ch, one wave per edge ----------------
__global__ __launch_bounds__(256) void scatter2_kernel(
    const int* __restrict__ src, const int* __restrict__ dst,
    const float* __restrict__ dinv, const float* __restrict__ h,
    float* __restrict__ out, int E) {
  int gw = (blockIdx.x * blockDim.x + threadIdx.x) >> 6;
  int lane = threadIdx.x & 63;
  if (gw >= E) return;
  int s = src[gw], d = dst[gw];
  float norm = dinv[s] * dinv[d];
  if (lane < 40) {
    float v = h[(size_t)s * 40 + lane];
    atomicAdd(out + (size_t)d * 40 + lane, v * norm);
  }
}

extern "C" void kernel_launch(void* const* d_in, const int* in_sizes, int n_in,
                              void* d_out, int out_size, void* d_ws, size_t ws_size,
                              hipStream_t stream) {
  const float* x  = (const float*)d_in[0];
  const int*  ei  = (const int*)d_in[1];
  const float* W1 = (const float*)d_in[2];
  const float* b1 = (const float*)d_in[3];
  const float* W2 = (const float*)d_in[4];
  const float* b2 = (const float*)d_in[5];
  const int* src = ei;
  const int* dst = ei + N_EDGES;
  float* out = (float*)d_out;

  float* ws = (float*)d_ws;
  float* dinv = ws;                                    // N floats (deg then dinv)
  float* h1   = ws + 100096;                           // N*128
  float* agg1 = h1 + (size_t)N_NODES * 128;            // N*128
  float* h2   = agg1 + (size_t)N_NODES * 128;          // N*40

  hipMemsetAsync(dinv, 0, N_NODES * sizeof(float), stream);
  hipMemsetAsync(agg1, 0, (size_t)N_NODES * 128 * sizeof(float), stream);

  deg_count_kernel<<<2048, 256, 0, stream>>>(dst, dinv, N_EDGES);
  dinv_kernel<<<(N_NODES + 255) / 256, 256, 0, stream>>>(dinv, N_NODES);

  gemm1_kernel<<<(N_NODES + 63) / 64, 256, 0, stream>>>(x, W1, h1, N_NODES);

  scatter1_kernel<<<N_EDGES / 4, 256, 0, stream>>>(src, dst, dinv, h1, agg1, N_EDGES);
  finalize1_kernel<<<(N_NODES * 32 + 255) / 256, 256, 0, stream>>>(agg1, h1, dinv, b1, N_NODES * 32);

  gemm2_kernel<<<(N_NODES + 127) / 128, 256, 0, stream>>>(agg1, W2, h2, N_NODES);

  outinit_kernel<<<(N_NODES * 40 + 255) / 256, 256, 0, stream>>>(out, h2, dinv, b2, N_NODES * 40);
  scatter2_kernel<<<N_EDGES / 4, 256, 0, stream>>>(src, dst, dinv, h2, out, N_EDGES);
}

// Round 2
// 710.600 us; speedup vs baseline: 2.7437x; 2.7437x over previous
//
#include <hip/hip_runtime.h>

#define N_NODES 100000
#define N_EDGES 1600000
// dims: in 256, hid 128, out 40

// ---------------- degree histogram (int atomics) ----------------
__global__ __launch_bounds__(256) void hist_kernel(
    const int* __restrict__ dst, int* __restrict__ degcnt, int E) {
  int i = blockIdx.x * blockDim.x + threadIdx.x;
  int stride = gridDim.x * blockDim.x;
  for (; i < E; i += stride) atomicAdd(&degcnt[dst[i]], 1);
}

__global__ __launch_bounds__(256) void dinv_kernel(
    const int* __restrict__ degcnt, float* __restrict__ dinv, int n) {
  int i = blockIdx.x * blockDim.x + threadIdx.x;
  if (i < n) dinv[i] = rsqrtf(1.0f + (float)degcnt[i]);
}

// ---------------- 3-kernel exclusive scan: rowstart[i+1] = sum deg[0..i] ----------------
__global__ __launch_bounds__(256) void scan1_kernel(
    const int* __restrict__ deg, int* __restrict__ rowstart, int* __restrict__ bsum, int n) {
  __shared__ int lds[256];
  int base = blockIdx.x * 512;
  int t = threadIdx.x;
  int i0 = base + t * 2, i1 = i0 + 1;
  int a = (i0 < n) ? deg[i0] : 0;
  int b = (i1 < n) ? deg[i1] : 0;
  int pairsum = a + b;
  lds[t] = pairsum;
  __syncthreads();
#pragma unroll
  for (int off = 1; off < 256; off <<= 1) {
    int v = lds[t];
    int add = (t >= off) ? lds[t - off] : 0;
    __syncthreads();
    lds[t] = v + add;
    __syncthreads();
  }
  int prev = (t > 0) ? lds[t - 1] : 0;
  if (i0 < n) rowstart[i0 + 1] = prev + a;
  if (i1 < n) rowstart[i1 + 1] = prev + pairsum;
  if (t == 255) bsum[blockIdx.x] = lds[255];
}

__global__ __launch_bounds__(256) void scan2_kernel(int* __restrict__ bsum, int nb) {
  __shared__ int lds[256];
  int t = threadIdx.x;
  lds[t] = (t < nb) ? bsum[t] : 0;
  __syncthreads();
#pragma unroll
  for (int off = 1; off < 256; off <<= 1) {
    int v = lds[t];
    int add = (t >= off) ? lds[t - off] : 0;
    __syncthreads();
    lds[t] = v + add;
    __syncthreads();
  }
  if (t < nb) bsum[t] = (t > 0) ? lds[t - 1] : 0;
}

__global__ __launch_bounds__(256) void scan3_kernel(
    int* __restrict__ rowstart, const int* __restrict__ bsum, int n) {
  int i = blockIdx.x * blockDim.x + threadIdx.x;
  if (i < n) rowstart[i + 1] += bsum[i >> 9];
  if (i == 0) rowstart[0] = 0;
}

// ---------------- CSR fill ----------------
__global__ __launch_bounds__(256) void fill_kernel(
    const int* __restrict__ src, const int* __restrict__ dst,
    const float* __restrict__ dinv, const int* __restrict__ rowstart,
    int* __restrict__ cursor, int* __restrict__ csr_src, float* __restrict__ csr_norm, int E) {
  int i = blockIdx.x * blockDim.x + threadIdx.x;
  int stride = gridDim.x * blockDim.x;
  for (; i < E; i += stride) {
    int s = src[i], d = dst[i];
    int pos = rowstart[d] + atomicAdd(&cursor[d], 1);
    csr_src[pos] = s;
    csr_norm[pos] = dinv[s] * dinv[d];
  }
}

// ---------------- GEMM1: [M,256] @ [256,128] -> [M,128] ----------------
__global__ __launch_bounds__(256) void gemm1_kernel(
    const float* __restrict__ A, const float* __restrict__ B,
    float* __restrict__ C, int M) {
  __shared__ float As[32][68];
  __shared__ float Bs[32][128];
  const int tid = threadIdx.x;
  const int row0 = blockIdx.x * 64;
  const int tc = tid & 31;
  const int tr = tid >> 5;
  float acc[8][4];
#pragma unroll
  for (int r = 0; r < 8; ++r)
#pragma unroll
    for (int c = 0; c < 4; ++c) acc[r][c] = 0.f;

  for (int kt = 0; kt < 256; kt += 32) {
#pragma unroll
    for (int l = 0; l < 2; ++l) {
      int s = tid + l * 256;
      int row = s >> 3;
      int kq = s & 7;
      int rg = min(row0 + row, M - 1);
      float4 v = *(const float4*)(A + (size_t)rg * 256 + kt + kq * 4);
      As[kq * 4 + 0][row] = v.x;
      As[kq * 4 + 1][row] = v.y;
      As[kq * 4 + 2][row] = v.z;
      As[kq * 4 + 3][row] = v.w;
    }
#pragma unroll
    for (int l = 0; l < 4; ++l) {
      int s = tid + l * 256;
      int k = s >> 5;
      int cq = s & 31;
      *(float4*)(&Bs[k][cq * 4]) = *(const float4*)(B + (size_t)(kt + k) * 128 + cq * 4);
    }
    __syncthreads();
#pragma unroll
    for (int k = 0; k < 32; ++k) {
      float4 b = *(const float4*)(&Bs[k][tc * 4]);
      float4 a0 = *(const float4*)(&As[k][tr * 8]);
      float4 a1 = *(const float4*)(&As[k][tr * 8 + 4]);
      float av[8] = {a0.x, a0.y, a0.z, a0.w, a1.x, a1.y, a1.z, a1.w};
      float bv[4] = {b.x, b.y, b.z, b.w};
#pragma unroll
      for (int r = 0; r < 8; ++r)
#pragma unroll
        for (int c = 0; c < 4; ++c) acc[r][c] += av[r] * bv[c];
    }
    __syncthreads();
  }
#pragma unroll
  for (int r = 0; r < 8; ++r) {
    int row = row0 + tr * 8 + r;
    if (row < M) {
      float4 v = make_float4(acc[r][0], acc[r][1], acc[r][2], acc[r][3]);
      *(float4*)(C + (size_t)row * 128 + tc * 4) = v;
    }
  }
}

// ---------------- gather layer 1 (fused self-loop + bias + ReLU) ----------------
// one wave per node; 2 edges/iter (half-waves); float4 per lane over 128 ch
__global__ __launch_bounds__(256) void gather1_kernel(
    const int* __restrict__ rowstart, const int* __restrict__ csr_src,
    const float* __restrict__ csr_norm, const float* __restrict__ dinv,
    const float* __restrict__ h, const float* __restrict__ bias,
    float* __restrict__ out, int n) {
  int w = (blockIdx.x * blockDim.x + threadIdx.x) >> 6;
  int lane = threadIdx.x & 63;
  if (w >= n) return;
  int beg = rowstart[w], end = rowstart[w + 1];
  int half = lane >> 5;
  int cq = (lane & 31) * 4;
  float4 acc = make_float4(0.f, 0.f, 0.f, 0.f);
  for (int e0 = beg; e0 < end; e0 += 2) {
    int e = e0 + half;
    if (e < end) {
      int s = csr_src[e];
      float norm = csr_norm[e];
      float4 v = *(const float4*)(h + (size_t)s * 128 + cq);
      acc.x += v.x * norm; acc.y += v.y * norm;
      acc.z += v.z * norm; acc.w += v.w * norm;
    }
  }
  acc.x += __shfl_xor(acc.x, 32);
  acc.y += __shfl_xor(acc.y, 32);
  acc.z += __shfl_xor(acc.z, 32);
  acc.w += __shfl_xor(acc.w, 32);
  if (half == 0) {
    float di = dinv[w];
    float sl = di * di;
    float4 hv = *(const float4*)(h + (size_t)w * 128 + cq);
    float4 bv = *(const float4*)(bias + cq);
    float4 r;
    r.x = fmaxf(acc.x + hv.x * sl + bv.x, 0.f);
    r.y = fmaxf(acc.y + hv.y * sl + bv.y, 0.f);
    r.z = fmaxf(acc.z + hv.z * sl + bv.z, 0.f);
    r.w = fmaxf(acc.w + hv.w * sl + bv.w, 0.f);
    *(float4*)(out + (size_t)w * 128 + cq) = r;
  }
}

// ---------------- GEMM2: [M,128] @ [128,40] -> [M,40] ----------------
__global__ __launch_bounds__(256) void gemm2_kernel(
    const float* __restrict__ A, const float* __restrict__ B,
    float* __restrict__ C, int M) {
  __shared__ float As[32][132];
  __shared__ float Bs[128][40];
  const int tid = threadIdx.x;
  const int row0 = blockIdx.x * 128;
#pragma unroll
  for (int l = 0; l < 5; ++l) {
    int s = tid + l * 256;
    *(float4*)((float*)Bs + (size_t)s * 4) = *(const float4*)(B + (size_t)s * 4);
  }
  const int tc = tid & 7;
  const int tr = tid >> 3;
  float acc[4][5];
#pragma unroll
  for (int r = 0; r < 4; ++r)
#pragma unroll
    for (int j = 0; j < 5; ++j) acc[r][j] = 0.f;

  for (int kt = 0; kt < 128; kt += 32) {
#pragma unroll
    for (int l = 0; l < 4; ++l) {
      int s = tid + l * 256;
      int row = s >> 3;
      int kq = s & 7;
      int rg = min(row0 + row, M - 1);
      float4 v = *(const float4*)(A + (size_t)rg * 128 + kt + kq * 4);
      As[kq * 4 + 0][row] = v.x;
      As[kq * 4 + 1][row] = v.y;
      As[kq * 4 + 2][row] = v.z;
      As[kq * 4 + 3][row] = v.w;
    }
    __syncthreads();
#pragma unroll
    for (int k = 0; k < 32; ++k) {
      float4 a = *(const float4*)(&As[k][tr * 4]);
      float av[4] = {a.x, a.y, a.z, a.w};
#pragma unroll
      for (int j = 0; j < 5; ++j) {
        float bv = Bs[kt + k][tc + 8 * j];
#pragma unroll
        for (int r = 0; r < 4; ++r) acc[r][j] += av[r] * bv;
      }
    }
    __syncthreads();
  }
#pragma unroll
  for (int r = 0; r < 4; ++r) {
    int row = row0 + tr * 4 + r;
    if (row < M) {
#pragma unroll
      for (int j = 0; j < 5; ++j) C[(size_t)row * 40 + tc + 8 * j] = acc[r][j];
    }
  }
}

// ---------------- gather layer 2 (fused self-loop + bias) ----------------
__global__ __launch_bounds__(256) void gather2_kernel(
    const int* __restrict__ rowstart, const int* __restrict__ csr_src,
    const float* __restrict__ csr_norm, const float* __restrict__ dinv,
    const float* __restrict__ h, const float* __restrict__ bias,
    float* __restrict__ out, int n) {
  int w = (blockIdx.x * blockDim.x + threadIdx.x) >> 6;
  int lane = threadIdx.x & 63;
  if (w >= n) return;
  int beg = rowstart[w], end = rowstart[w + 1];
  bool act = lane < 40;
  float acc = 0.f;
  for (int e = beg; e < end; ++e) {
    int s = csr_src[e];
    float norm = csr_norm[e];
    if (act) acc += h[(size_t)s * 40 + lane] * norm;
  }
  if (act) {
    float di = dinv[w];
    out[(size_t)w * 40 + lane] = acc + h[(size_t)w * 40 + lane] * di * di + bias[lane];
  }
}

extern "C" void kernel_launch(void* const* d_in, const int* in_sizes, int n_in,
                              void* d_out, int out_size, void* d_ws, size_t ws_size,
                              hipStream_t stream) {
  const float* x  = (const float*)d_in[0];
  const int*  ei  = (const int*)d_in[1];
  const float* W1 = (const float*)d_in[2];
  const float* b1 = (const float*)d_in[3];
  const float* W2 = (const float*)d_in[4];
  const float* b2 = (const float*)d_in[5];
  const int* src = ei;
  const int* dst = ei + N_EDGES;
  float* out = (float*)d_out;

  char* ws = (char*)d_ws;
  int*   degcnt   = (int*)(ws);                         // 100096 ints (reused as cursor)
  float* dinv     = (float*)(ws + 400384);              // 100096 floats
  int*   rowstart = (int*)(ws + 800768);                // 100352 ints
  int*   bsum     = (int*)(ws + 1202176);               // 256 ints
  int*   csr_src  = (int*)(ws + 1203200);               // 1.6M ints
  float* csr_norm = (float*)(ws + 7603200);             // 1.6M floats
  float* h1       = (float*)(ws + 14003200);            // 12.8M floats
  float* agg1     = h1 + (size_t)N_NODES * 128;         // 12.8M floats
  float* h2       = agg1 + (size_t)N_NODES * 128;       // 4M floats

  // --- CSR build ---
  hipMemsetAsync(degcnt, 0, N_NODES * sizeof(int), stream);
  hist_kernel<<<2048, 256, 0, stream>>>(dst, degcnt, N_EDGES);
  dinv_kernel<<<(N_NODES + 255) / 256, 256, 0, stream>>>(degcnt, dinv, N_NODES);
  scan1_kernel<<<196, 256, 0, stream>>>(degcnt, rowstart, bsum, N_NODES);
  scan2_kernel<<<1, 256, 0, stream>>>(bsum, 196);
  scan3_kernel<<<(N_NODES + 255) / 256, 256, 0, stream>>>(rowstart, bsum, N_NODES);
  hipMemsetAsync(degcnt, 0, N_NODES * sizeof(int), stream);  // reuse as cursor
  fill_kernel<<<2048, 256, 0, stream>>>(src, dst, dinv, rowstart, degcnt, csr_src, csr_norm, N_EDGES);

  // --- layer 1 ---
  gemm1_kernel<<<(N_NODES + 63) / 64, 256, 0, stream>>>(x, W1, h1, N_NODES);
  gather1_kernel<<<25000, 256, 0, stream>>>(rowstart, csr_src, csr_norm, dinv, h1, b1, agg1, N_NODES);

  // --- layer 2 ---
  gemm2_kernel<<<(N_NODES + 127) / 128, 256, 0, stream>>>(agg1, W2, h2, N_NODES);
  gather2_kernel<<<25000, 256, 0, stream>>>(rowstart, csr_src, csr_norm, dinv, h2, b2, out, N_NODES);
}

// Round 4
// 622.395 us; speedup vs baseline: 3.1326x; 1.1417x over previous
//
#include <hip/hip_runtime.h>

#define N_NODES 100000
#define N_EDGES 1600000
// dims: in 256, hid 128, out 40

// ---------------- degree histogram (int atomics) ----------------
__global__ __launch_bounds__(256) void hist_kernel(
    const int* __restrict__ dst, int* __restrict__ degcnt, int E) {
  int i = blockIdx.x * blockDim.x + threadIdx.x;
  int stride = gridDim.x * blockDim.x;
  for (; i < E; i += stride) atomicAdd(&degcnt[dst[i]], 1);
}

__global__ __launch_bounds__(256) void dinv_kernel(
    const int* __restrict__ degcnt, float* __restrict__ dinv, int n) {
  int i = blockIdx.x * blockDim.x + threadIdx.x;
  if (i < n) dinv[i] = rsqrtf(1.0f + (float)degcnt[i]);
}

// ---------------- 3-kernel exclusive scan: rowstart[i+1] = sum deg[0..i] ----------------
__global__ __launch_bounds__(256) void scan1_kernel(
    const int* __restrict__ deg, int* __restrict__ rowstart, int* __restrict__ bsum, int n) {
  __shared__ int lds[256];
  int base = blockIdx.x * 512;
  int t = threadIdx.x;
  int i0 = base + t * 2, i1 = i0 + 1;
  int a = (i0 < n) ? deg[i0] : 0;
  int b = (i1 < n) ? deg[i1] : 0;
  int pairsum = a + b;
  lds[t] = pairsum;
  __syncthreads();
#pragma unroll
  for (int off = 1; off < 256; off <<= 1) {
    int v = lds[t];
    int add = (t >= off) ? lds[t - off] : 0;
    __syncthreads();
    lds[t] = v + add;
    __syncthreads();
  }
  int prev = (t > 0) ? lds[t - 1] : 0;
  if (i0 < n) rowstart[i0 + 1] = prev + a;
  if (i1 < n) rowstart[i1 + 1] = prev + pairsum;
  if (t == 255) bsum[blockIdx.x] = lds[255];
}

__global__ __launch_bounds__(256) void scan2_kernel(int* __restrict__ bsum, int nb) {
  __shared__ int lds[256];
  int t = threadIdx.x;
  lds[t] = (t < nb) ? bsum[t] : 0;
  __syncthreads();
#pragma unroll
  for (int off = 1; off < 256; off <<= 1) {
    int v = lds[t];
    int add = (t >= off) ? lds[t - off] : 0;
    __syncthreads();
    lds[t] = v + add;
    __syncthreads();
  }
  if (t < nb) bsum[t] = (t > 0) ? lds[t - 1] : 0;
}

__global__ __launch_bounds__(256) void scan3_kernel(
    int* __restrict__ rowstart, const int* __restrict__ bsum, int n) {
  int i = blockIdx.x * blockDim.x + threadIdx.x;
  if (i < n) rowstart[i + 1] += bsum[i >> 9];
  if (i == 0) rowstart[0] = 0;
}

// ---------------- CSR fill ----------------
__global__ __launch_bounds__(256) void fill_kernel(
    const int* __restrict__ src, const int* __restrict__ dst,
    const float* __restrict__ dinv, const int* __restrict__ rowstart,
    int* __restrict__ cursor, int* __restrict__ csr_src, float* __restrict__ csr_norm, int E) {
  int i = blockIdx.x * blockDim.x + threadIdx.x;
  int stride = gridDim.x * blockDim.x;
  for (; i < E; i += stride) {
    int s = src[i], d = dst[i];
    int pos = rowstart[d] + atomicAdd(&cursor[d], 1);
    csr_src[pos] = s;
    csr_norm[pos] = dinv[s] * dinv[d];
  }
}

// ---------------- GEMM1: [M,256] @ [256,128] -> [M,128] ----------------
__global__ __launch_bounds__(256) void gemm1_kernel(
    const float* __restrict__ A, const float* __restrict__ B,
    float* __restrict__ C, int M) {
  __shared__ float As[32][68];
  __shared__ float Bs[32][128];
  const int tid = threadIdx.x;
  const int row0 = blockIdx.x * 64;
  const int tc = tid & 31;
  const int tr = tid >> 5;
  float acc[8][4];
#pragma unroll
  for (int r = 0; r < 8; ++r)
#pragma unroll
    for (int c = 0; c < 4; ++c) acc[r][c] = 0.f;

  for (int kt = 0; kt < 256; kt += 32) {
#pragma unroll
    for (int l = 0; l < 2; ++l) {
      int s = tid + l * 256;
      int row = s >> 3;
      int kq = s & 7;
      int rg = min(row0 + row, M - 1);
      float4 v = *(const float4*)(A + (size_t)rg * 256 + kt + kq * 4);
      As[kq * 4 + 0][row] = v.x;
      As[kq * 4 + 1][row] = v.y;
      As[kq * 4 + 2][row] = v.z;
      As[kq * 4 + 3][row] = v.w;
    }
#pragma unroll
    for (int l = 0; l < 4; ++l) {
      int s = tid + l * 256;
      int k = s >> 5;
      int cq = s & 31;
      *(float4*)(&Bs[k][cq * 4]) = *(const float4*)(B + (size_t)(kt + k) * 128 + cq * 4);
    }
    __syncthreads();
#pragma unroll
    for (int k = 0; k < 32; ++k) {
      float4 b = *(const float4*)(&Bs[k][tc * 4]);
      float4 a0 = *(const float4*)(&As[k][tr * 8]);
      float4 a1 = *(const float4*)(&As[k][tr * 8 + 4]);
      float av[8] = {a0.x, a0.y, a0.z, a0.w, a1.x, a1.y, a1.z, a1.w};
      float bv[4] = {b.x, b.y, b.z, b.w};
#pragma unroll
      for (int r = 0; r < 8; ++r)
#pragma unroll
        for (int c = 0; c < 4; ++c) acc[r][c] += av[r] * bv[c];
    }
    __syncthreads();
  }
#pragma unroll
  for (int r = 0; r < 8; ++r) {
    int row = row0 + tr * 8 + r;
    if (row < M) {
      float4 v = make_float4(acc[r][0], acc[r][1], acc[r][2], acc[r][3]);
      *(float4*)(C + (size_t)row * 128 + tc * 4) = v;
    }
  }
}

// ---------------- gather layer 1 (fused self-loop + bias + ReLU) ----------------
// one wave per node; quarter-wave per edge (4 edges/iter, 8 edges with unroll2);
// each lane holds 8 channels (two float4)
__global__ __launch_bounds__(256) void gather1_kernel(
    const int* __restrict__ rowstart, const int* __restrict__ csr_src,
    const float* __restrict__ csr_norm, const float* __restrict__ dinv,
    const float* __restrict__ h, const float* __restrict__ bias,
    float* __restrict__ out, int n) {
  int w = (blockIdx.x * blockDim.x + threadIdx.x) >> 6;
  int lane = threadIdx.x & 63;
  if (w >= n) return;
  int beg = rowstart[w], end = rowstart[w + 1];
  int q = lane >> 4;          // quarter 0..3
  int cq = (lane & 15) * 8;   // 8 channels per lane
  float4 a0 = make_float4(0.f, 0.f, 0.f, 0.f);
  float4 a1 = make_float4(0.f, 0.f, 0.f, 0.f);
  float4 a2 = make_float4(0.f, 0.f, 0.f, 0.f);
  float4 a3 = make_float4(0.f, 0.f, 0.f, 0.f);
  for (int e0 = beg; e0 < end; e0 += 8) {
    int ea = e0 + q;
    int eb = e0 + 4 + q;
    int ca = min(ea, end - 1);
    int cb = min(eb, end - 1);
    float na = (ea < end) ? csr_norm[ca] : 0.f;
    float nb = (eb < end) ? csr_norm[cb] : 0.f;
    int sa = csr_src[ca];
    int sb = csr_src[cb];
    const float* pa = h + (size_t)sa * 128 + cq;
    const float* pb = h + (size_t)sb * 128 + cq;
    float4 va0 = *(const float4*)(pa);
    float4 va1 = *(const float4*)(pa + 4);
    float4 vb0 = *(const float4*)(pb);
    float4 vb1 = *(const float4*)(pb + 4);
    a0.x += va0.x * na; a0.y += va0.y * na; a0.z += va0.z * na; a0.w += va0.w * na;
    a1.x += va1.x * na; a1.y += va1.y * na; a1.z += va1.z * na; a1.w += va1.w * na;
    a2.x += vb0.x * nb; a2.y += vb0.y * nb; a2.z += vb0.z * nb; a2.w += vb0.w * nb;
    a3.x += vb1.x * nb; a3.y += vb1.y * nb; a3.z += vb1.z * nb; a3.w += vb1.w * nb;
  }
  a0.x += a2.x; a0.y += a2.y; a0.z += a2.z; a0.w += a2.w;
  a1.x += a3.x; a1.y += a3.y; a1.z += a3.z; a1.w += a3.w;
  // reduce across 4 quarters
#pragma unroll
  for (int off = 16; off < 64; off <<= 1) {
    a0.x += __shfl_xor(a0.x, off);
    a0.y += __shfl_xor(a0.y, off);
    a0.z += __shfl_xor(a0.z, off);
    a0.w += __shfl_xor(a0.w, off);
    a1.x += __shfl_xor(a1.x, off);
    a1.y += __shfl_xor(a1.y, off);
    a1.z += __shfl_xor(a1.z, off);
    a1.w += __shfl_xor(a1.w, off);
  }
  if (q == 0) {
    float di = dinv[w];
    float sl = di * di;
    const float* hp = h + (size_t)w * 128 + cq;
    float4 h0 = *(const float4*)(hp);
    float4 h1v = *(const float4*)(hp + 4);
    float4 b0 = *(const float4*)(bias + cq);
    float4 b1v = *(const float4*)(bias + cq + 4);
    float4 r0, r1;
    r0.x = fmaxf(a0.x + h0.x * sl + b0.x, 0.f);
    r0.y = fmaxf(a0.y + h0.y * sl + b0.y, 0.f);
    r0.z = fmaxf(a0.z + h0.z * sl + b0.z, 0.f);
    r0.w = fmaxf(a0.w + h0.w * sl + b0.w, 0.f);
    r1.x = fmaxf(a1.x + h1v.x * sl + b1v.x, 0.f);
    r1.y = fmaxf(a1.y + h1v.y * sl + b1v.y, 0.f);
    r1.z = fmaxf(a1.z + h1v.z * sl + b1v.z, 0.f);
    r1.w = fmaxf(a1.w + h1v.w * sl + b1v.w, 0.f);
    float* op = out + (size_t)w * 128 + cq;
    *(float4*)(op) = r0;
    *(float4*)(op + 4) = r1;
  }
}

// ---------------- GEMM2: [M,128] @ [128,40] -> [M,40] ----------------
__global__ __launch_bounds__(256) void gemm2_kernel(
    const float* __restrict__ A, const float* __restrict__ B,
    float* __restrict__ C, int M) {
  __shared__ float As[32][132];
  __shared__ float Bs[128][40];
  const int tid = threadIdx.x;
  const int row0 = blockIdx.x * 128;
#pragma unroll
  for (int l = 0; l < 5; ++l) {
    int s = tid + l * 256;
    *(float4*)((float*)Bs + (size_t)s * 4) = *(const float4*)(B + (size_t)s * 4);
  }
  const int tc = tid & 7;
  const int tr = tid >> 3;
  float acc[4][5];
#pragma unroll
  for (int r = 0; r < 4; ++r)
#pragma unroll
    for (int j = 0; j < 5; ++j) acc[r][j] = 0.f;

  for (int kt = 0; kt < 128; kt += 32) {
#pragma unroll
    for (int l = 0; l < 4; ++l) {
      int s = tid + l * 256;
      int row = s >> 3;
      int kq = s & 7;
      int rg = min(row0 + row, M - 1);
      float4 v = *(const float4*)(A + (size_t)rg * 128 + kt + kq * 4);
      As[kq * 4 + 0][row] = v.x;
      As[kq * 4 + 1][row] = v.y;
      As[kq * 4 + 2][row] = v.z;
      As[kq * 4 + 3][row] = v.w;
    }
    __syncthreads();
#pragma unroll
    for (int k = 0; k < 32; ++k) {
      float4 a = *(const float4*)(&As[k][tr * 4]);
      float av[4] = {a.x, a.y, a.z, a.w};
#pragma unroll
      for (int j = 0; j < 5; ++j) {
        float bv = Bs[kt + k][tc + 8 * j];
#pragma unroll
        for (int r = 0; r < 4; ++r) acc[r][j] += av[r] * bv;
      }
    }
    __syncthreads();
  }
#pragma unroll
  for (int r = 0; r < 4; ++r) {
    int row = row0 + tr * 4 + r;
    if (row < M) {
#pragma unroll
      for (int j = 0; j < 5; ++j) C[(size_t)row * 40 + tc + 8 * j] = acc[r][j];
    }
  }
}

// ---------------- gather layer 2 (fused self-loop + bias), 4-edge unroll ----------------
__global__ __launch_bounds__(256) void gather2_kernel(
    const int* __restrict__ rowstart, const int* __restrict__ csr_src,
    const float* __restrict__ csr_norm, const float* __restrict__ dinv,
    const float* __restrict__ h, const float* __restrict__ bias,
    float* __restrict__ out, int n) {
  int w = (blockIdx.x * blockDim.x + threadIdx.x) >> 6;
  int lane = threadIdx.x & 63;
  if (w >= n) return;
  int beg = rowstart[w], end = rowstart[w + 1];
  if (lane >= 40) return;
  float acc0 = 0.f, acc1 = 0.f, acc2 = 0.f, acc3 = 0.f;
  for (int e0 = beg; e0 < end; e0 += 4) {
    int e1 = e0 + 1, e2 = e0 + 2, e3 = e0 + 3;
    int c1 = min(e1, end - 1);
    int c2 = min(e2, end - 1);
    int c3 = min(e3, end - 1);
    float n0 = csr_norm[e0];
    float n1 = (e1 < end) ? csr_norm[c1] : 0.f;
    float n2 = (e2 < end) ? csr_norm[c2] : 0.f;
    float n3 = (e3 < end) ? csr_norm[c3] : 0.f;
    int s0 = csr_src[e0];
    int s1 = csr_src[c1];
    int s2 = csr_src[c2];
    int s3 = csr_src[c3];
    float v0 = h[(size_t)s0 * 40 + lane];
    float v1 = h[(size_t)s1 * 40 + lane];
    float v2 = h[(size_t)s2 * 40 + lane];
    float v3 = h[(size_t)s3 * 40 + lane];
    acc0 += v0 * n0;
    acc1 += v1 * n1;
    acc2 += v2 * n2;
    acc3 += v3 * n3;
  }
  float di = dinv[w];
  float acc = (acc0 + acc1) + (acc2 + acc3);
  out[(size_t)w * 40 + lane] = acc + h[(size_t)w * 40 + lane] * di * di + bias[lane];
}

extern "C" void kernel_launch(void* const* d_in, const int* in_sizes, int n_in,
                              void* d_out, int out_size, void* d_ws, size_t ws_size,
                              hipStream_t stream) {
  const float* x  = (const float*)d_in[0];
  const int*  ei  = (const int*)d_in[1];
  const float* W1 = (const float*)d_in[2];
  const float* b1 = (const float*)d_in[3];
  const float* W2 = (const float*)d_in[4];
  const float* b2 = (const float*)d_in[5];
  const int* src = ei;
  const int* dst = ei + N_EDGES;
  float* out = (float*)d_out;

  char* ws = (char*)d_ws;
  int*   degcnt   = (int*)(ws);                         // 100096 ints (reused as cursor)
  float* dinv     = (float*)(ws + 400384);              // 100096 floats
  int*   rowstart = (int*)(ws + 800768);                // 100352 ints
  int*   bsum     = (int*)(ws + 1202176);               // 256 ints
  int*   csr_src  = (int*)(ws + 1203200);               // 1.6M ints
  float* csr_norm = (float*)(ws + 7603200);             // 1.6M floats
  float* h1       = (float*)(ws + 14003200);            // 12.8M floats
  float* agg1     = h1 + (size_t)N_NODES * 128;         // 12.8M floats
  float* h2       = agg1 + (size_t)N_NODES * 128;       // 4M floats

  // --- CSR build ---
  hipMemsetAsync(degcnt, 0, N_NODES * sizeof(int), stream);
  hist_kernel<<<2048, 256, 0, stream>>>(dst, degcnt, N_EDGES);
  dinv_kernel<<<(N_NODES + 255) / 256, 256, 0, stream>>>(degcnt, dinv, N_NODES);
  scan1_kernel<<<196, 256, 0, stream>>>(degcnt, rowstart, bsum, N_NODES);
  scan2_kernel<<<1, 256, 0, stream>>>(bsum, 196);
  scan3_kernel<<<(N_NODES + 255) / 256, 256, 0, stream>>>(rowstart, bsum, N_NODES);
  hipMemsetAsync(degcnt, 0, N_NODES * sizeof(int), stream);  // reuse as cursor
  fill_kernel<<<2048, 256, 0, stream>>>(src, dst, dinv, rowstart, degcnt, csr_src, csr_norm, N_EDGES);

  // --- layer 1 ---
  gemm1_kernel<<<(N_NODES + 63) / 64, 256, 0, stream>>>(x, W1, h1, N_NODES);
  gather1_kernel<<<25000, 256, 0, stream>>>(rowstart, csr_src, csr_norm, dinv, h1, b1, agg1, N_NODES);

  // --- layer 2 ---
  gemm2_kernel<<<(N_NODES + 127) / 128, 256, 0, stream>>>(agg1, W2, h2, N_NODES);
  gather2_kernel<<<25000, 256, 0, stream>>>(rowstart, csr_src, csr_norm, dinv, h2, b2, out, N_NODES);
}

// Round 6
// 506.407 us; speedup vs baseline: 3.8500x; 1.2290x over previous
//
#include <hip/hip_runtime.h>

#define N_NODES 100000
#define N_EDGES 1600000
// dims: in 256, hid 128, out 40

typedef unsigned int u32;
typedef unsigned short u16;
typedef __attribute__((ext_vector_type(8))) short bf16x8;
typedef __attribute__((ext_vector_type(4))) float f32x4;

__device__ __forceinline__ u16 f2b(float f) {
  u32 u = __builtin_bit_cast(u32, f);
  u32 r = (u + 0x7FFFu + ((u >> 16) & 1u)) >> 16;
  return (u16)r;
}
__device__ __forceinline__ float b2f(u32 bits) {
  return __builtin_bit_cast(float, bits << 16);
}
__device__ __forceinline__ u32 pack2(float x, float y) {
  return (u32)f2b(x) | ((u32)f2b(y) << 16);
}

// ---------------- degree histogram (int atomics) ----------------
__global__ __launch_bounds__(256) void hist_kernel(
    const int* __restrict__ dst, int* __restrict__ degcnt, int E) {
  int i = blockIdx.x * blockDim.x + threadIdx.x;
  int stride = gridDim.x * blockDim.x;
  for (; i < E; i += stride) atomicAdd(&degcnt[dst[i]], 1);
}

__global__ __launch_bounds__(256) void dinv_kernel(
    const int* __restrict__ degcnt, float* __restrict__ dinv, int n) {
  int i = blockIdx.x * blockDim.x + threadIdx.x;
  if (i < n) dinv[i] = rsqrtf(1.0f + (float)degcnt[i]);
}

// ---------------- 3-kernel exclusive scan ----------------
__global__ __launch_bounds__(256) void scan1_kernel(
    const int* __restrict__ deg, int* __restrict__ rowstart, int* __restrict__ bsum, int n) {
  __shared__ int lds[256];
  int base = blockIdx.x * 512;
  int t = threadIdx.x;
  int i0 = base + t * 2, i1 = i0 + 1;
  int a = (i0 < n) ? deg[i0] : 0;
  int b = (i1 < n) ? deg[i1] : 0;
  int pairsum = a + b;
  lds[t] = pairsum;
  __syncthreads();
#pragma unroll
  for (int off = 1; off < 256; off <<= 1) {
    int v = lds[t];
    int add = (t >= off) ? lds[t - off] : 0;
    __syncthreads();
    lds[t] = v + add;
    __syncthreads();
  }
  int prev = (t > 0) ? lds[t - 1] : 0;
  if (i0 < n) rowstart[i0 + 1] = prev + a;
  if (i1 < n) rowstart[i1 + 1] = prev + pairsum;
  if (t == 255) bsum[blockIdx.x] = lds[255];
}

__global__ __launch_bounds__(256) void scan2_kernel(int* __restrict__ bsum, int nb) {
  __shared__ int lds[256];
  int t = threadIdx.x;
  lds[t] = (t < nb) ? bsum[t] : 0;
  __syncthreads();
#pragma unroll
  for (int off = 1; off < 256; off <<= 1) {
    int v = lds[t];
    int add = (t >= off) ? lds[t - off] : 0;
    __syncthreads();
    lds[t] = v + add;
    __syncthreads();
  }
  if (t < nb) bsum[t] = (t > 0) ? lds[t - 1] : 0;
}

__global__ __launch_bounds__(256) void scan3_kernel(
    int* __restrict__ rowstart, const int* __restrict__ bsum, int n) {
  int i = blockIdx.x * blockDim.x + threadIdx.x;
  if (i < n) rowstart[i + 1] += bsum[i >> 9];
  if (i == 0) rowstart[0] = 0;
}

// ---------------- CSR fill ----------------
__global__ __launch_bounds__(256) void fill_kernel(
    const int* __restrict__ src, const int* __restrict__ dst,
    const float* __restrict__ dinv, const int* __restrict__ rowstart,
    int* __restrict__ cursor, int* __restrict__ csr_src, float* __restrict__ csr_norm, int E) {
  int i = blockIdx.x * blockDim.x + threadIdx.x;
  int stride = gridDim.x * blockDim.x;
  for (; i < E; i += stride) {
    int s = src[i], d = dst[i];
    int pos = rowstart[d] + atomicAdd(&cursor[d], 1);
    csr_src[pos] = s;
    csr_norm[pos] = dinv[s] * dinv[d];
  }
}

// ---------------- weight precasts ----------------
// W1 [256,128] f32 -> Bt [128][256] bf16 (transposed)
__global__ __launch_bounds__(256) void cast_w1_kernel(
    const float* __restrict__ W, u16* __restrict__ Bt) {
  int i = blockIdx.x * 256 + threadIdx.x;   // 32768 total
  int c = i & 127, k = i >> 7;
  Bt[c * 256 + k] = f2b(W[k * 128 + c]);
}
// W2 [128,40] f32 -> Bt [48][128] bf16 (transposed, cols 40..47 zero)
__global__ __launch_bounds__(256) void cast_w2_kernel(
    const float* __restrict__ W, u16* __restrict__ Bt) {
  int i = blockIdx.x * 256 + threadIdx.x;   // 6144 total
  int c = i >> 7, k = i & 127;
  float v = (c < 40) ? W[k * 40 + c] : 0.f;
  Bt[c * 128 + k] = f2b(v);
}

// ---------------- GEMM1 (bf16 MFMA): x[M,256] @ W1 -> h1 bf16 [M,128] ----------------
// BM=64, BN=128, BK=32, 256 thr = 4 waves, wave w owns rows w*16..+15
// LDS rows padded to 40 bf16 (80 B): 16-row frag reads are 2-way conflicts (free)
__global__ __launch_bounds__(256) void gemm1_kernel(
    const float* __restrict__ A, const u16* __restrict__ Bt,
    u16* __restrict__ Cb, int M) {
  __shared__ __align__(16) u16 As[64 * 40];
  __shared__ __align__(16) u16 Bs[128 * 40];
  const int tid = threadIdx.x;
  const int row0 = blockIdx.x * 64;
  const int w = tid >> 6, l = tid & 63;
  const int lr = l & 15, lk = l >> 4;
  f32x4 acc[8];
#pragma unroll
  for (int n = 0; n < 8; ++n) acc[n] = (f32x4){0.f, 0.f, 0.f, 0.f};

  const int arow = tid >> 2;          // 0..63
  const int akq = (tid & 3) * 8;      // k offset (floats)
  const int ag = min(row0 + arow, M - 1);
  const float* ap0 = A + (size_t)ag * 256 + akq;
  const int bcol = tid >> 1;          // 0..127
  const int bko = (tid & 1) * 16;     // k offset (elements)
  const u16* bp0 = Bt + (size_t)bcol * 256 + bko;

  for (int kt = 0; kt < 256; kt += 32) {
    float4 v0 = *(const float4*)(ap0 + kt);
    float4 v1 = *(const float4*)(ap0 + kt + 4);
    uint4 ac;
    ac.x = pack2(v0.x, v0.y);
    ac.y = pack2(v0.z, v0.w);
    ac.z = pack2(v1.x, v1.y);
    ac.w = pack2(v1.z, v1.w);
    *(uint4*)(&As[arow * 40 + akq]) = ac;
    const uint4* bp = (const uint4*)(bp0 + kt);
    uint4 b0 = bp[0];
    uint4 b1 = bp[1];
    *(uint4*)(&Bs[bcol * 40 + bko]) = b0;
    *(uint4*)(&Bs[bcol * 40 + bko + 8]) = b1;
    __syncthreads();
    bf16x8 af = *(const bf16x8*)(&As[(w * 16 + lr) * 40 + lk * 8]);
#pragma unroll
    for (int n = 0; n < 8; ++n) {
      bf16x8 bf = *(const bf16x8*)(&Bs[(n * 16 + lr) * 40 + lk * 8]);
      acc[n] = __builtin_amdgcn_mfma_f32_16x16x32_bf16(af, bf, acc[n], 0, 0, 0);
    }
    __syncthreads();
  }
  const int orow = row0 + w * 16 + (l >> 4) * 4;
#pragma unroll
  for (int n = 0; n < 8; ++n) {
#pragma unroll
    for (int i = 0; i < 4; ++i) {
      int r = orow + i;
      if (r < M) Cb[(size_t)r * 128 + n * 16 + lr] = f2b(acc[n][i]);
    }
  }
}

// ---------------- gather layer 1 (bf16 table, fused self-loop+bias+ReLU) ----------------
// one wave per node; quarter-wave per edge, 8 edges/iter; 8 ch/lane (16 B loads)
__global__ __launch_bounds__(256) void gather1_kernel(
    const int* __restrict__ rowstart, const int* __restrict__ csr_src,
    const float* __restrict__ csr_norm, const float* __restrict__ dinv,
    const u16* __restrict__ hb, const float* __restrict__ bias,
    u16* __restrict__ outb, int n) {
  int w = (blockIdx.x * blockDim.x + threadIdx.x) >> 6;
  int lane = threadIdx.x & 63;
  if (w >= n) return;
  int beg = rowstart[w], end = rowstart[w + 1];
  int q = lane >> 4;
  int cq = (lane & 15) * 8;
  float a0[8], a1[8];
#pragma unroll
  for (int j = 0; j < 8; ++j) { a0[j] = 0.f; a1[j] = 0.f; }
  for (int e0 = beg; e0 < end; e0 += 8) {
    int ea = e0 + q;
    int eb = e0 + 4 + q;
    int ca = min(ea, end - 1);
    int cb = min(eb, end - 1);
    float na = (ea < end) ? csr_norm[ca] : 0.f;
    float nb = (eb < end) ? csr_norm[cb] : 0.f;
    int sa = csr_src[ca];
    int sb = csr_src[cb];
    uint4 va = *(const uint4*)(hb + (size_t)sa * 128 + cq);
    uint4 vb = *(const uint4*)(hb + (size_t)sb * 128 + cq);
    const u32* pa = (const u32*)&va;
    const u32* pb = (const u32*)&vb;
#pragma unroll
    for (int j = 0; j < 4; ++j) {
      a0[2 * j]     += b2f(pa[j] & 0xffffu) * na;
      a0[2 * j + 1] += b2f(pa[j] >> 16) * na;
      a1[2 * j]     += b2f(pb[j] & 0xffffu) * nb;
      a1[2 * j + 1] += b2f(pb[j] >> 16) * nb;
    }
  }
#pragma unroll
  for (int j = 0; j < 8; ++j) a0[j] += a1[j];
#pragma unroll
  for (int off = 16; off < 64; off <<= 1) {
#pragma unroll
    for (int j = 0; j < 8; ++j) a0[j] += __shfl_xor(a0[j], off);
  }
  if (q == 0) {
    float di = dinv[w];
    float sl = di * di;
    uint4 hv = *(const uint4*)(hb + (size_t)w * 128 + cq);
    const u32* ph = (const u32*)&hv;
    float4 b0 = *(const float4*)(bias + cq);
    float4 b1v = *(const float4*)(bias + cq + 4);
    float bb[8] = {b0.x, b0.y, b0.z, b0.w, b1v.x, b1v.y, b1v.z, b1v.w};
    float r[8];
#pragma unroll
    for (int j = 0; j < 4; ++j) {
      r[2 * j]     = fmaxf(a0[2 * j]     + b2f(ph[j] & 0xffffu) * sl + bb[2 * j], 0.f);
      r[2 * j + 1] = fmaxf(a0[2 * j + 1] + b2f(ph[j] >> 16)     * sl + bb[2 * j + 1], 0.f);
    }
    uint4 o;
    o.x = pack2(r[0], r[1]);
    o.y = pack2(r[2], r[3]);
    o.z = pack2(r[4], r[5]);
    o.w = pack2(r[6], r[7]);
    *(uint4*)(outb + (size_t)w * 128 + cq) = o;
  }
}

// ---------------- GEMM2 (bf16 MFMA): agg1b[M,128] @ W2 -> h2 bf16 [M,40] ----------------
// BM=64, BN=48 (pad), K=128; A frags straight from global (each row read once)
__global__ __launch_bounds__(256) void gemm2_kernel(
    const u16* __restrict__ Ab, const u16* __restrict__ Bt,
    u16* __restrict__ Cb, int M) {
  __shared__ __align__(16) u16 Bs[48 * 136];
  const int tid = threadIdx.x;
  const int row0 = blockIdx.x * 64;
  const int w = tid >> 6, l = tid & 63;
  const int lr = l & 15, lk = l >> 4;
  // stage W2^T: 48 cols x 128 k = 768 chunks of 8 u16; 16 chunks per col
#pragma unroll
  for (int i = 0; i < 3; ++i) {
    int ch = tid + i * 256;
    int col = ch >> 4;            // 0..47
    int ko = (ch & 15) * 8;       // 0..120
    *(uint4*)(&Bs[col * 136 + ko]) = *(const uint4*)(Bt + col * 128 + ko);
  }
  __syncthreads();
  f32x4 acc[3];
#pragma unroll
  for (int n = 0; n < 3; ++n) acc[n] = (f32x4){0.f, 0.f, 0.f, 0.f};
  const int arow = min(row0 + w * 16 + lr, M - 1);
  const u16* ap = Ab + (size_t)arow * 128 + lk * 8;
#pragma unroll
  for (int kt = 0; kt < 4; ++kt) {
    bf16x8 af = *(const bf16x8*)(ap + kt * 32);
#pragma unroll
    for (int n = 0; n < 3; ++n) {
      bf16x8 bf = *(const bf16x8*)(&Bs[(n * 16 + lr) * 136 + kt * 32 + lk * 8]);
      acc[n] = __builtin_amdgcn_mfma_f32_16x16x32_bf16(af, bf, acc[n], 0, 0, 0);
    }
  }
  const int orow = row0 + w * 16 + (l >> 4) * 4;
#pragma unroll
  for (int n = 0; n < 3; ++n) {
    int c = n * 16 + lr;
    if (c < 40) {
#pragma unroll
      for (int i = 0; i < 4; ++i) {
        int r = orow + i;
        if (r < M) Cb[(size_t)r * 40 + c] = f2b(acc[n][i]);
      }
    }
  }
}

// ---------------- gather layer 2 (bf16 table, fused self-loop + bias) ----------------
__global__ __launch_bounds__(256) void gather2_kernel(
    const int* __restrict__ rowstart, const int* __restrict__ csr_src,
    const float* __restrict__ csr_norm, const float* __restrict__ dinv,
    const u16* __restrict__ hb, const float* __restrict__ bias,
    float* __restrict__ out, int n) {
  int w = (blockIdx.x * blockDim.x + threadIdx.x) >> 6;
  int lane = threadIdx.x & 63;
  if (w >= n || lane >= 40) return;
  int beg = rowstart[w], end = rowstart[w + 1];
  float acc0 = 0.f, acc1 = 0.f, acc2 = 0.f, acc3 = 0.f;
  for (int e0 = beg; e0 < end; e0 += 4) {
    int c1 = min(e0 + 1, end - 1);
    int c2 = min(e0 + 2, end - 1);
    int c3 = min(e0 + 3, end - 1);
    float n0 = csr_norm[e0];
    float n1 = (e0 + 1 < end) ? csr_norm[c1] : 0.f;
    float n2 = (e0 + 2 < end) ? csr_norm[c2] : 0.f;
    float n3 = (e0 + 3 < end) ? csr_norm[c3] : 0.f;
    int s0 = csr_src[e0], s1 = csr_src[c1], s2 = csr_src[c2], s3 = csr_src[c3];
    acc0 += b2f(hb[(size_t)s0 * 40 + lane]) * n0;
    acc1 += b2f(hb[(size_t)s1 * 40 + lane]) * n1;
    acc2 += b2f(hb[(size_t)s2 * 40 + lane]) * n2;
    acc3 += b2f(hb[(size_t)s3 * 40 + lane]) * n3;
  }
  float di = dinv[w];
  out[(size_t)w * 40 + lane] =
      (acc0 + acc1) + (acc2 + acc3) + b2f(hb[(size_t)w * 40 + lane]) * di * di + bias[lane];
}

extern "C" void kernel_launch(void* const* d_in, const int* in_sizes, int n_in,
                              void* d_out, int out_size, void* d_ws, size_t ws_size,
                              hipStream_t stream) {
  const float* x  = (const float*)d_in[0];
  const int*  ei  = (const int*)d_in[1];
  const float* W1 = (const float*)d_in[2];
  const float* b1 = (const float*)d_in[3];
  const float* W2 = (const float*)d_in[4];
  const float* b2 = (const float*)d_in[5];
  const int* src = ei;
  const int* dst = ei + N_EDGES;
  float* out = (float*)d_out;

  char* ws = (char*)d_ws;
  int*   degcnt   = (int*)(ws);                 // 100096 ints (reused as cursor)
  float* dinv     = (float*)(ws + 400384);      // 100096 f32
  int*   rowstart = (int*)(ws + 800768);        // 100352 ints
  int*   bsum     = (int*)(ws + 1202176);       // 256 ints
  int*   csr_src  = (int*)(ws + 1203200);       // 1.6M ints
  float* csr_norm = (float*)(ws + 7603200);     // 1.6M f32
  u16*   w1t      = (u16*)(ws + 14003200);      // 128*256 bf16 = 65536 B
  u16*   w2t      = (u16*)(ws + 14068736);      // 48*128 bf16 = 12288 B
  u16*   h1b      = (u16*)(ws + 14081024);      // N*128 bf16 = 25.6 MB
  u16*   agg1b    = (u16*)(ws + 39681024);      // N*128 bf16 = 25.6 MB
  u16*   h2b      = (u16*)(ws + 65281024);      // N*40 bf16 = 8 MB

  // --- weight precasts (independent) ---
  cast_w1_kernel<<<128, 256, 0, stream>>>(W1, w1t);
  cast_w2_kernel<<<24, 256, 0, stream>>>(W2, w2t);

  // --- CSR build ---
  hipMemsetAsync(degcnt, 0, N_NODES * sizeof(int), stream);
  hist_kernel<<<2048, 256, 0, stream>>>(dst, degcnt, N_EDGES);
  dinv_kernel<<<(N_NODES + 255) / 256, 256, 0, stream>>>(degcnt, dinv, N_NODES);
  scan1_kernel<<<196, 256, 0, stream>>>(degcnt, rowstart, bsum, N_NODES);
  scan2_kernel<<<1, 256, 0, stream>>>(bsum, 196);
  scan3_kernel<<<(N_NODES + 255) / 256, 256, 0, stream>>>(rowstart, bsum, N_NODES);
  hipMemsetAsync(degcnt, 0, N_NODES * sizeof(int), stream);  // reuse as cursor
  fill_kernel<<<2048, 256, 0, stream>>>(src, dst, dinv, rowstart, degcnt, csr_src, csr_norm, N_EDGES);

  // --- layer 1 ---
  gemm1_kernel<<<(N_NODES + 63) / 64, 256, 0, stream>>>(x, w1t, h1b, N_NODES);
  gather1_kernel<<<25000, 256, 0, stream>>>(rowstart, csr_src, csr_norm, dinv, h1b, b1, agg1b, N_NODES);

  // --- layer 2 ---
  gemm2_kernel<<<(N_NODES + 63) / 64, 256, 0, stream>>>(agg1b, w2t, h2b, N_NODES);
  gather2_kernel<<<25000, 256, 0, stream>>>(rowstart, csr_src, csr_norm, dinv, h2b, b2, out, N_NODES);
}

// Round 7
// 456.316 us; speedup vs baseline: 4.2727x; 1.1098x over previous
//
#include <hip/hip_runtime.h>

#define N_NODES 100000
#define N_EDGES 1600000
// dims: in 256, hid 128, out 40

typedef unsigned int u32;
typedef unsigned short u16;
typedef __attribute__((ext_vector_type(8))) short bf16x8;
typedef __attribute__((ext_vector_type(4))) float f32x4;

__device__ __forceinline__ u16 f2b(float f) {
  u32 u = __builtin_bit_cast(u32, f);
  u32 r = (u + 0x7FFFu + ((u >> 16) & 1u)) >> 16;
  return (u16)r;
}
__device__ __forceinline__ float b2f(u32 bits) {
  return __builtin_bit_cast(float, bits << 16);
}
__device__ __forceinline__ u32 pack2(float x, float y) {
  return (u32)f2b(x) | ((u32)f2b(y) << 16);
}

// ---------------- histogram + per-edge rank (single atomic pass) ----------------
__global__ __launch_bounds__(256) void hist_rank_kernel(
    const int* __restrict__ dst, int* __restrict__ degcnt, int* __restrict__ rank, int E) {
  int i = blockIdx.x * blockDim.x + threadIdx.x;
  int stride = gridDim.x * blockDim.x;
  for (; i < E; i += stride) rank[i] = atomicAdd(&degcnt[dst[i]], 1);
}

__global__ __launch_bounds__(256) void dinv_kernel(
    const int* __restrict__ degcnt, float* __restrict__ dinv, int n) {
  int i = blockIdx.x * blockDim.x + threadIdx.x;
  if (i < n) dinv[i] = rsqrtf(1.0f + (float)degcnt[i]);
}

// ---------------- 3-kernel exclusive scan ----------------
__global__ __launch_bounds__(256) void scan1_kernel(
    const int* __restrict__ deg, int* __restrict__ rowstart, int* __restrict__ bsum, int n) {
  __shared__ int lds[256];
  int base = blockIdx.x * 512;
  int t = threadIdx.x;
  int i0 = base + t * 2, i1 = i0 + 1;
  int a = (i0 < n) ? deg[i0] : 0;
  int b = (i1 < n) ? deg[i1] : 0;
  int pairsum = a + b;
  lds[t] = pairsum;
  __syncthreads();
#pragma unroll
  for (int off = 1; off < 256; off <<= 1) {
    int v = lds[t];
    int add = (t >= off) ? lds[t - off] : 0;
    __syncthreads();
    lds[t] = v + add;
    __syncthreads();
  }
  int prev = (t > 0) ? lds[t - 1] : 0;
  if (i0 < n) rowstart[i0 + 1] = prev + a;
  if (i1 < n) rowstart[i1 + 1] = prev + pairsum;
  if (t == 255) bsum[blockIdx.x] = lds[255];
}

__global__ __launch_bounds__(256) void scan2_kernel(int* __restrict__ bsum, int nb) {
  __shared__ int lds[256];
  int t = threadIdx.x;
  lds[t] = (t < nb) ? bsum[t] : 0;
  __syncthreads();
#pragma unroll
  for (int off = 1; off < 256; off <<= 1) {
    int v = lds[t];
    int add = (t >= off) ? lds[t - off] : 0;
    __syncthreads();
    lds[t] = v + add;
    __syncthreads();
  }
  if (t < nb) bsum[t] = (t > 0) ? lds[t - 1] : 0;
}

__global__ __launch_bounds__(256) void scan3_kernel(
    int* __restrict__ rowstart, const int* __restrict__ bsum, int n) {
  int i = blockIdx.x * blockDim.x + threadIdx.x;
  if (i < n) rowstart[i + 1] += bsum[i >> 9];
  if (i == 0) rowstart[0] = 0;
}

// ---------------- CSR scatter-fill (no atomics): csr[pos] = {src, norm} ----------------
__global__ __launch_bounds__(256) void scatter_fill_kernel(
    const int* __restrict__ src, const int* __restrict__ dst,
    const int* __restrict__ rank, const float* __restrict__ dinv,
    const int* __restrict__ rowstart, int2* __restrict__ csr, int E) {
  int i = blockIdx.x * blockDim.x + threadIdx.x;
  int stride = gridDim.x * blockDim.x;
  for (; i < E; i += stride) {
    int s = src[i], d = dst[i];
    float norm = dinv[s] * dinv[d];
    int pos = rowstart[d] + rank[i];
    csr[pos] = make_int2(s, __builtin_bit_cast(int, norm));
  }
}

// ---------------- weight precasts ----------------
// W1 [256,128] f32 -> Bt [128][256] bf16 (transposed)
__global__ __launch_bounds__(256) void cast_w1_kernel(
    const float* __restrict__ W, u16* __restrict__ Bt) {
  int i = blockIdx.x * 256 + threadIdx.x;   // 32768 total
  int c = i & 127, k = i >> 7;
  Bt[c * 256 + k] = f2b(W[k * 128 + c]);
}
// W2 [128,40] f32 -> Bt [48][128] bf16 (transposed, cols 40..47 zero)
__global__ __launch_bounds__(256) void cast_w2_kernel(
    const float* __restrict__ W, u16* __restrict__ Bt) {
  int i = blockIdx.x * 256 + threadIdx.x;   // 6144 total
  int c = i >> 7, k = i & 127;
  float v = (c < 40) ? W[k * 40 + c] : 0.f;
  Bt[c * 128 + k] = f2b(v);
}

// ---------------- GEMM1 (bf16 MFMA): x[M,256] @ W1 -> h1 bf16 [M,128] ----------------
__global__ __launch_bounds__(256) void gemm1_kernel(
    const float* __restrict__ A, const u16* __restrict__ Bt,
    u16* __restrict__ Cb, int M) {
  __shared__ __align__(16) u16 As[64 * 40];
  __shared__ __align__(16) u16 Bs[128 * 40];
  const int tid = threadIdx.x;
  const int row0 = blockIdx.x * 64;
  const int w = tid >> 6, l = tid & 63;
  const int lr = l & 15, lk = l >> 4;
  f32x4 acc[8];
#pragma unroll
  for (int n = 0; n < 8; ++n) acc[n] = (f32x4){0.f, 0.f, 0.f, 0.f};

  const int arow = tid >> 2;
  const int akq = (tid & 3) * 8;
  const int ag = min(row0 + arow, M - 1);
  const float* ap0 = A + (size_t)ag * 256 + akq;
  const int bcol = tid >> 1;
  const int bko = (tid & 1) * 16;
  const u16* bp0 = Bt + (size_t)bcol * 256 + bko;

  for (int kt = 0; kt < 256; kt += 32) {
    float4 v0 = *(const float4*)(ap0 + kt);
    float4 v1 = *(const float4*)(ap0 + kt + 4);
    uint4 ac;
    ac.x = pack2(v0.x, v0.y);
    ac.y = pack2(v0.z, v0.w);
    ac.z = pack2(v1.x, v1.y);
    ac.w = pack2(v1.z, v1.w);
    *(uint4*)(&As[arow * 40 + akq]) = ac;
    const uint4* bp = (const uint4*)(bp0 + kt);
    uint4 b0 = bp[0];
    uint4 b1 = bp[1];
    *(uint4*)(&Bs[bcol * 40 + bko]) = b0;
    *(uint4*)(&Bs[bcol * 40 + bko + 8]) = b1;
    __syncthreads();
    bf16x8 af = *(const bf16x8*)(&As[(w * 16 + lr) * 40 + lk * 8]);
#pragma unroll
    for (int n = 0; n < 8; ++n) {
      bf16x8 bf = *(const bf16x8*)(&Bs[(n * 16 + lr) * 40 + lk * 8]);
      acc[n] = __builtin_amdgcn_mfma_f32_16x16x32_bf16(af, bf, acc[n], 0, 0, 0);
    }
    __syncthreads();
  }
  const int orow = row0 + w * 16 + (l >> 4) * 4;
#pragma unroll
  for (int n = 0; n < 8; ++n) {
#pragma unroll
    for (int i = 0; i < 4; ++i) {
      int r = orow + i;
      if (r < M) Cb[(size_t)r * 128 + n * 16 + lr] = f2b(acc[n][i]);
    }
  }
}

// ---------------- gather layer 1 (bf16 table, fused self-loop+bias+ReLU) ----------------
__global__ __launch_bounds__(256) void gather1_kernel(
    const int* __restrict__ rowstart, const int2* __restrict__ csr,
    const float* __restrict__ dinv,
    const u16* __restrict__ hb, const float* __restrict__ bias,
    u16* __restrict__ outb, int n) {
  int w = (blockIdx.x * blockDim.x + threadIdx.x) >> 6;
  int lane = threadIdx.x & 63;
  if (w >= n) return;
  int beg = rowstart[w], end = rowstart[w + 1];
  int q = lane >> 4;
  int cq = (lane & 15) * 8;
  float a0[8], a1[8];
#pragma unroll
  for (int j = 0; j < 8; ++j) { a0[j] = 0.f; a1[j] = 0.f; }
  for (int e0 = beg; e0 < end; e0 += 8) {
    int ea = e0 + q;
    int eb = e0 + 4 + q;
    int ca = min(ea, end - 1);
    int cb = min(eb, end - 1);
    int2 ta = csr[ca];
    int2 tb = csr[cb];
    float na = (ea < end) ? __builtin_bit_cast(float, ta.y) : 0.f;
    float nb = (eb < end) ? __builtin_bit_cast(float, tb.y) : 0.f;
    int sa = ta.x;
    int sb = tb.x;
    uint4 va = *(const uint4*)(hb + (size_t)sa * 128 + cq);
    uint4 vb = *(const uint4*)(hb + (size_t)sb * 128 + cq);
    const u32* pa = (const u32*)&va;
    const u32* pb = (const u32*)&vb;
#pragma unroll
    for (int j = 0; j < 4; ++j) {
      a0[2 * j]     += b2f(pa[j] & 0xffffu) * na;
      a0[2 * j + 1] += b2f(pa[j] >> 16) * na;
      a1[2 * j]     += b2f(pb[j] & 0xffffu) * nb;
      a1[2 * j + 1] += b2f(pb[j] >> 16) * nb;
    }
  }
#pragma unroll
  for (int j = 0; j < 8; ++j) a0[j] += a1[j];
#pragma unroll
  for (int off = 16; off < 64; off <<= 1) {
#pragma unroll
    for (int j = 0; j < 8; ++j) a0[j] += __shfl_xor(a0[j], off);
  }
  if (q == 0) {
    float di = dinv[w];
    float sl = di * di;
    uint4 hv = *(const uint4*)(hb + (size_t)w * 128 + cq);
    const u32* ph = (const u32*)&hv;
    float4 b0 = *(const float4*)(bias + cq);
    float4 b1v = *(const float4*)(bias + cq + 4);
    float bb[8] = {b0.x, b0.y, b0.z, b0.w, b1v.x, b1v.y, b1v.z, b1v.w};
    float r[8];
#pragma unroll
    for (int j = 0; j < 4; ++j) {
      r[2 * j]     = fmaxf(a0[2 * j]     + b2f(ph[j] & 0xffffu) * sl + bb[2 * j], 0.f);
      r[2 * j + 1] = fmaxf(a0[2 * j + 1] + b2f(ph[j] >> 16)     * sl + bb[2 * j + 1], 0.f);
    }
    uint4 o;
    o.x = pack2(r[0], r[1]);
    o.y = pack2(r[2], r[3]);
    o.z = pack2(r[4], r[5]);
    o.w = pack2(r[6], r[7]);
    *(uint4*)(outb + (size_t)w * 128 + cq) = o;
  }
}

// ---------------- GEMM2 (bf16 MFMA): agg1b[M,128] @ W2 -> h2 bf16 [M,40] ----------------
__global__ __launch_bounds__(256) void gemm2_kernel(
    const u16* __restrict__ Ab, const u16* __restrict__ Bt,
    u16* __restrict__ Cb, int M) {
  __shared__ __align__(16) u16 Bs[48 * 136];
  const int tid = threadIdx.x;
  const int row0 = blockIdx.x * 64;
  const int w = tid >> 6, l = tid & 63;
  const int lr = l & 15, lk = l >> 4;
#pragma unroll
  for (int i = 0; i < 3; ++i) {
    int ch = tid + i * 256;
    int col = ch >> 4;
    int ko = (ch & 15) * 8;
    *(uint4*)(&Bs[col * 136 + ko]) = *(const uint4*)(Bt + col * 128 + ko);
  }
  __syncthreads();
  f32x4 acc[3];
#pragma unroll
  for (int n = 0; n < 3; ++n) acc[n] = (f32x4){0.f, 0.f, 0.f, 0.f};
  const int arow = min(row0 + w * 16 + lr, M - 1);
  const u16* ap = Ab + (size_t)arow * 128 + lk * 8;
#pragma unroll
  for (int kt = 0; kt < 4; ++kt) {
    bf16x8 af = *(const bf16x8*)(ap + kt * 32);
#pragma unroll
    for (int n = 0; n < 3; ++n) {
      bf16x8 bf = *(const bf16x8*)(&Bs[(n * 16 + lr) * 136 + kt * 32 + lk * 8]);
      acc[n] = __builtin_amdgcn_mfma_f32_16x16x32_bf16(af, bf, acc[n], 0, 0, 0);
    }
  }
  const int orow = row0 + w * 16 + (l >> 4) * 4;
#pragma unroll
  for (int n = 0; n < 3; ++n) {
    int c = n * 16 + lr;
    if (c < 40) {
#pragma unroll
      for (int i = 0; i < 4; ++i) {
        int r = orow + i;
        if (r < M) Cb[(size_t)r * 40 + c] = f2b(acc[n][i]);
      }
    }
  }
}

// ---------------- gather layer 2 (bf16 table, fused self-loop + bias) ----------------
__global__ __launch_bounds__(256) void gather2_kernel(
    const int* __restrict__ rowstart, const int2* __restrict__ csr,
    const float* __restrict__ dinv,
    const u16* __restrict__ hb, const float* __restrict__ bias,
    float* __restrict__ out, int n) {
  int w = (blockIdx.x * blockDim.x + threadIdx.x) >> 6;
  int lane = threadIdx.x & 63;
  if (w >= n || lane >= 40) return;
  int beg = rowstart[w], end = rowstart[w + 1];
  float acc0 = 0.f, acc1 = 0.f, acc2 = 0.f, acc3 = 0.f;
  for (int e0 = beg; e0 < end; e0 += 4) {
    int c1 = min(e0 + 1, end - 1);
    int c2 = min(e0 + 2, end - 1);
    int c3 = min(e0 + 3, end - 1);
    int2 t0 = csr[e0];
    int2 t1 = csr[c1];
    int2 t2 = csr[c2];
    int2 t3 = csr[c3];
    float n0 = __builtin_bit_cast(float, t0.y);
    float n1 = (e0 + 1 < end) ? __builtin_bit_cast(float, t1.y) : 0.f;
    float n2 = (e0 + 2 < end) ? __builtin_bit_cast(float, t2.y) : 0.f;
    float n3 = (e0 + 3 < end) ? __builtin_bit_cast(float, t3.y) : 0.f;
    acc0 += b2f(hb[(size_t)t0.x * 40 + lane]) * n0;
    acc1 += b2f(hb[(size_t)t1.x * 40 + lane]) * n1;
    acc2 += b2f(hb[(size_t)t2.x * 40 + lane]) * n2;
    acc3 += b2f(hb[(size_t)t3.x * 40 + lane]) * n3;
  }
  float di = dinv[w];
  out[(size_t)w * 40 + lane] =
      (acc0 + acc1) + (acc2 + acc3) + b2f(hb[(size_t)w * 40 + lane]) * di * di + bias[lane];
}

extern "C" void kernel_launch(void* const* d_in, const int* in_sizes, int n_in,
                              void* d_out, int out_size, void* d_ws, size_t ws_size,
                              hipStream_t stream) {
  const float* x  = (const float*)d_in[0];
  const int*  ei  = (const int*)d_in[1];
  const float* W1 = (const float*)d_in[2];
  const float* b1 = (const float*)d_in[3];
  const float* W2 = (const float*)d_in[4];
  const float* b2 = (const float*)d_in[5];
  const int* src = ei;
  const int* dst = ei + N_EDGES;
  float* out = (float*)d_out;

  char* ws = (char*)d_ws;
  int*   degcnt   = (int*)(ws);                 // 100096 ints
  float* dinv     = (float*)(ws + 400384);      // 100096 f32
  int*   rowstart = (int*)(ws + 800768);        // 100352 ints
  int*   bsum     = (int*)(ws + 1202176);       // 256 ints
  int2*  csr      = (int2*)(ws + 1203200);      // 1.6M int2 = 12.8 MB -> ends 14003200
  u16*   w1t      = (u16*)(ws + 14003200);      // 65536 B
  u16*   w2t      = (u16*)(ws + 14068736);      // 12288 B
  u16*   h1b      = (u16*)(ws + 14081024);      // N*128 bf16 = 25.6 MB
  u16*   agg1b    = (u16*)(ws + 39681024);      // N*128 bf16 = 25.6 MB
  u16*   h2b      = (u16*)(ws + 65281024);      // N*40 bf16 = 8 MB
  int*   rank     = (int*)(ws + 65281024);      // 6.4 MB, ALIASES h2b slot
  // (rank used only in hist_rank->scatter_fill, before gemm2 writes h2b — disjoint in time)

  // --- weight precasts (independent) ---
  cast_w1_kernel<<<128, 256, 0, stream>>>(W1, w1t);
  cast_w2_kernel<<<24, 256, 0, stream>>>(W2, w2t);

  // --- CSR build: single atomic pass ---
  hipMemsetAsync(degcnt, 0, N_NODES * sizeof(int), stream);
  hist_rank_kernel<<<2048, 256, 0, stream>>>(dst, degcnt, rank, N_EDGES);
  dinv_kernel<<<(N_NODES + 255) / 256, 256, 0, stream>>>(degcnt, dinv, N_NODES);
  scan1_kernel<<<196, 256, 0, stream>>>(degcnt, rowstart, bsum, N_NODES);
  scan2_kernel<<<1, 256, 0, stream>>>(bsum, 196);
  scan3_kernel<<<(N_NODES + 255) / 256, 256, 0, stream>>>(rowstart, bsum, N_NODES);
  scatter_fill_kernel<<<2048, 256, 0, stream>>>(src, dst, rank, dinv, rowstart, csr, N_EDGES);

  // --- layer 1 ---
  gemm1_kernel<<<(N_NODES + 63) / 64, 256, 0, stream>>>(x, w1t, h1b, N_NODES);
  gather1_kernel<<<25000, 256, 0, stream>>>(rowstart, csr, dinv, h1b, b1, agg1b, N_NODES);

  // --- layer 2 ---
  gemm2_kernel<<<(N_NODES + 63) / 64, 256, 0, stream>>>(agg1b, w2t, h2b, N_NODES);
  gather2_kernel<<<25000, 256, 0, stream>>>(rowstart, csr, dinv, h2b, b2, out, N_NODES);
}

// Round 8
// 453.506 us; speedup vs baseline: 4.2991x; 1.0062x over previous
//
#include <hip/hip_runtime.h>

#define N_NODES 100000
#define N_EDGES 1600000
// dims: in 256, hid 128, out 40

typedef unsigned int u32;
typedef unsigned short u16;
typedef __attribute__((ext_vector_type(8))) short bf16x8;
typedef __attribute__((ext_vector_type(4))) float f32x4;

__device__ __forceinline__ u16 f2b(float f) {
  u32 u = __builtin_bit_cast(u32, f);
  u32 r = (u + 0x7FFFu + ((u >> 16) & 1u)) >> 16;
  return (u16)r;
}
__device__ __forceinline__ float b2f(u32 bits) {
  return __builtin_bit_cast(float, bits << 16);
}
__device__ __forceinline__ u32 pack2(float x, float y) {
  return (u32)f2b(x) | ((u32)f2b(y) << 16);
}

// ---------------- histogram + per-edge rank (single atomic pass) ----------------
__global__ __launch_bounds__(256) void hist_rank_kernel(
    const int* __restrict__ dst, int* __restrict__ degcnt, int* __restrict__ rank, int E) {
  int i = blockIdx.x * blockDim.x + threadIdx.x;
  int stride = gridDim.x * blockDim.x;
  for (; i < E; i += stride) rank[i] = atomicAdd(&degcnt[dst[i]], 1);
}

__global__ __launch_bounds__(256) void dinv_kernel(
    const int* __restrict__ degcnt, float* __restrict__ dinv, int n) {
  int i = blockIdx.x * blockDim.x + threadIdx.x;
  if (i < n) dinv[i] = rsqrtf(1.0f + (float)degcnt[i]);
}

// ---------------- 3-kernel exclusive scan ----------------
__global__ __launch_bounds__(256) void scan1_kernel(
    const int* __restrict__ deg, int* __restrict__ rowstart, int* __restrict__ bsum, int n) {
  __shared__ int lds[256];
  int base = blockIdx.x * 512;
  int t = threadIdx.x;
  int i0 = base + t * 2, i1 = i0 + 1;
  int a = (i0 < n) ? deg[i0] : 0;
  int b = (i1 < n) ? deg[i1] : 0;
  int pairsum = a + b;
  lds[t] = pairsum;
  __syncthreads();
#pragma unroll
  for (int off = 1; off < 256; off <<= 1) {
    int v = lds[t];
    int add = (t >= off) ? lds[t - off] : 0;
    __syncthreads();
    lds[t] = v + add;
    __syncthreads();
  }
  int prev = (t > 0) ? lds[t - 1] : 0;
  if (i0 < n) rowstart[i0 + 1] = prev + a;
  if (i1 < n) rowstart[i1 + 1] = prev + pairsum;
  if (t == 255) bsum[blockIdx.x] = lds[255];
}

__global__ __launch_bounds__(256) void scan2_kernel(int* __restrict__ bsum, int nb) {
  __shared__ int lds[256];
  int t = threadIdx.x;
  lds[t] = (t < nb) ? bsum[t] : 0;
  __syncthreads();
#pragma unroll
  for (int off = 1; off < 256; off <<= 1) {
    int v = lds[t];
    int add = (t >= off) ? lds[t - off] : 0;
    __syncthreads();
    lds[t] = v + add;
    __syncthreads();
  }
  if (t < nb) bsum[t] = (t > 0) ? lds[t - 1] : 0;
}

__global__ __launch_bounds__(256) void scan3_kernel(
    int* __restrict__ rowstart, const int* __restrict__ bsum, int n) {
  int i = blockIdx.x * blockDim.x + threadIdx.x;
  if (i < n) rowstart[i + 1] += bsum[i >> 9];
  if (i == 0) rowstart[0] = 0;
}

// ---------------- CSR scatter-fill (no atomics): csr[pos] = {src, norm} ----------------
__global__ __launch_bounds__(256) void scatter_fill_kernel(
    const int* __restrict__ src, const int* __restrict__ dst,
    const int* __restrict__ rank, const float* __restrict__ dinv,
    const int* __restrict__ rowstart, int2* __restrict__ csr, int E) {
  int i = blockIdx.x * blockDim.x + threadIdx.x;
  int stride = gridDim.x * blockDim.x;
  for (; i < E; i += stride) {
    int s = src[i], d = dst[i];
    float norm = dinv[s] * dinv[d];
    int pos = rowstart[d] + rank[i];
    csr[pos] = make_int2(s, __builtin_bit_cast(int, norm));
  }
}

// ---------------- weight precasts ----------------
__global__ __launch_bounds__(256) void cast_w1_kernel(
    const float* __restrict__ W, u16* __restrict__ Bt) {
  int i = blockIdx.x * 256 + threadIdx.x;   // 32768 total
  int c = i & 127, k = i >> 7;
  Bt[c * 256 + k] = f2b(W[k * 128 + c]);
}
__global__ __launch_bounds__(256) void cast_w2_kernel(
    const float* __restrict__ W, u16* __restrict__ Bt) {
  int i = blockIdx.x * 256 + threadIdx.x;   // 6144 total
  int c = i >> 7, k = i & 127;
  float v = (c < 40) ? W[k * 40 + c] : 0.f;
  Bt[c * 128 + k] = f2b(v);
}

// ---------------- GEMM1 (bf16 MFMA): x[M,256] @ W1 -> h1 bf16 [M,128] ----------------
__global__ __launch_bounds__(256) void gemm1_kernel(
    const float* __restrict__ A, const u16* __restrict__ Bt,
    u16* __restrict__ Cb, int M) {
  __shared__ __align__(16) u16 As[64 * 40];
  __shared__ __align__(16) u16 Bs[128 * 40];
  const int tid = threadIdx.x;
  const int row0 = blockIdx.x * 64;
  const int w = tid >> 6, l = tid & 63;
  const int lr = l & 15, lk = l >> 4;
  f32x4 acc[8];
#pragma unroll
  for (int n = 0; n < 8; ++n) acc[n] = (f32x4){0.f, 0.f, 0.f, 0.f};

  const int arow = tid >> 2;
  const int akq = (tid & 3) * 8;
  const int ag = min(row0 + arow, M - 1);
  const float* ap0 = A + (size_t)ag * 256 + akq;
  const int bcol = tid >> 1;
  const int bko = (tid & 1) * 16;
  const u16* bp0 = Bt + (size_t)bcol * 256 + bko;

  for (int kt = 0; kt < 256; kt += 32) {
    float4 v0 = *(const float4*)(ap0 + kt);
    float4 v1 = *(const float4*)(ap0 + kt + 4);
    uint4 ac;
    ac.x = pack2(v0.x, v0.y);
    ac.y = pack2(v0.z, v0.w);
    ac.z = pack2(v1.x, v1.y);
    ac.w = pack2(v1.z, v1.w);
    *(uint4*)(&As[arow * 40 + akq]) = ac;
    const uint4* bp = (const uint4*)(bp0 + kt);
    uint4 b0 = bp[0];
    uint4 b1 = bp[1];
    *(uint4*)(&Bs[bcol * 40 + bko]) = b0;
    *(uint4*)(&Bs[bcol * 40 + bko + 8]) = b1;
    __syncthreads();
    bf16x8 af = *(const bf16x8*)(&As[(w * 16 + lr) * 40 + lk * 8]);
#pragma unroll
    for (int n = 0; n < 8; ++n) {
      bf16x8 bf = *(const bf16x8*)(&Bs[(n * 16 + lr) * 40 + lk * 8]);
      acc[n] = __builtin_amdgcn_mfma_f32_16x16x32_bf16(af, bf, acc[n], 0, 0, 0);
    }
    __syncthreads();
  }
  const int orow = row0 + w * 16 + (l >> 4) * 4;
#pragma unroll
  for (int n = 0; n < 8; ++n) {
#pragma unroll
    for (int i = 0; i < 4; ++i) {
      int r = orow + i;
      if (r < M) Cb[(size_t)r * 128 + n * 16 + lr] = f2b(acc[n][i]);
    }
  }
}

// ---------------- gather layer 1: 16 edges/iter (4 per quarter-wave) ----------------
__global__ __launch_bounds__(256) void gather1_kernel(
    const int* __restrict__ rowstart, const int2* __restrict__ csr,
    const float* __restrict__ dinv,
    const u16* __restrict__ hb, const float* __restrict__ bias,
    u16* __restrict__ outb, int n) {
  int w = (blockIdx.x * blockDim.x + threadIdx.x) >> 6;
  int lane = threadIdx.x & 63;
  if (w >= n) return;
  int beg = rowstart[w], end = rowstart[w + 1];
  int q = lane >> 4;
  int cq = (lane & 15) * 8;
  float a[4][8];
#pragma unroll
  for (int b = 0; b < 4; ++b)
#pragma unroll
    for (int j = 0; j < 8; ++j) a[b][j] = 0.f;

  for (int e0 = beg; e0 < end; e0 += 16) {
    int2 t0, t1, t2, t3;
    float n0, n1, n2, n3;
    {
      int e = e0 + q;           int c = min(e, end - 1);
      t0 = csr[c];  n0 = (e < end) ? __builtin_bit_cast(float, t0.y) : 0.f;
    }
    {
      int e = e0 + 4 + q;       int c = min(e, end - 1);
      t1 = csr[c];  n1 = (e < end) ? __builtin_bit_cast(float, t1.y) : 0.f;
    }
    {
      int e = e0 + 8 + q;       int c = min(e, end - 1);
      t2 = csr[c];  n2 = (e < end) ? __builtin_bit_cast(float, t2.y) : 0.f;
    }
    {
      int e = e0 + 12 + q;      int c = min(e, end - 1);
      t3 = csr[c];  n3 = (e < end) ? __builtin_bit_cast(float, t3.y) : 0.f;
    }
    uint4 v0 = *(const uint4*)(hb + (size_t)t0.x * 128 + cq);
    uint4 v1 = *(const uint4*)(hb + (size_t)t1.x * 128 + cq);
    uint4 v2 = *(const uint4*)(hb + (size_t)t2.x * 128 + cq);
    uint4 v3 = *(const uint4*)(hb + (size_t)t3.x * 128 + cq);
    const u32* p0 = (const u32*)&v0;
    const u32* p1 = (const u32*)&v1;
    const u32* p2 = (const u32*)&v2;
    const u32* p3 = (const u32*)&v3;
#pragma unroll
    for (int j = 0; j < 4; ++j) {
      a[0][2 * j]     += b2f(p0[j] & 0xffffu) * n0;
      a[0][2 * j + 1] += b2f(p0[j] >> 16) * n0;
      a[1][2 * j]     += b2f(p1[j] & 0xffffu) * n1;
      a[1][2 * j + 1] += b2f(p1[j] >> 16) * n1;
      a[2][2 * j]     += b2f(p2[j] & 0xffffu) * n2;
      a[2][2 * j + 1] += b2f(p2[j] >> 16) * n2;
      a[3][2 * j]     += b2f(p3[j] & 0xffffu) * n3;
      a[3][2 * j + 1] += b2f(p3[j] >> 16) * n3;
    }
  }
#pragma unroll
  for (int j = 0; j < 8; ++j) a[0][j] += (a[1][j] + a[2][j]) + a[3][j];
#pragma unroll
  for (int off = 16; off < 64; off <<= 1) {
#pragma unroll
    for (int j = 0; j < 8; ++j) a[0][j] += __shfl_xor(a[0][j], off);
  }
  if (q == 0) {
    float di = dinv[w];
    float sl = di * di;
    uint4 hv = *(const uint4*)(hb + (size_t)w * 128 + cq);
    const u32* ph = (const u32*)&hv;
    float4 b0 = *(const float4*)(bias + cq);
    float4 b1v = *(const float4*)(bias + cq + 4);
    float bb[8] = {b0.x, b0.y, b0.z, b0.w, b1v.x, b1v.y, b1v.z, b1v.w};
    float r[8];
#pragma unroll
    for (int j = 0; j < 4; ++j) {
      r[2 * j]     = fmaxf(a[0][2 * j]     + b2f(ph[j] & 0xffffu) * sl + bb[2 * j], 0.f);
      r[2 * j + 1] = fmaxf(a[0][2 * j + 1] + b2f(ph[j] >> 16)     * sl + bb[2 * j + 1], 0.f);
    }
    uint4 o;
    o.x = pack2(r[0], r[1]);
    o.y = pack2(r[2], r[3]);
    o.z = pack2(r[4], r[5]);
    o.w = pack2(r[6], r[7]);
    *(uint4*)(outb + (size_t)w * 128 + cq) = o;
  }
}

// ---------------- GEMM2 (bf16 MFMA): agg1b[M,128] @ W2 -> h2 bf16 [M,40] ----------------
__global__ __launch_bounds__(256) void gemm2_kernel(
    const u16* __restrict__ Ab, const u16* __restrict__ Bt,
    u16* __restrict__ Cb, int M) {
  __shared__ __align__(16) u16 Bs[48 * 136];
  const int tid = threadIdx.x;
  const int row0 = blockIdx.x * 64;
  const int w = tid >> 6, l = tid & 63;
  const int lr = l & 15, lk = l >> 4;
#pragma unroll
  for (int i = 0; i < 3; ++i) {
    int ch = tid + i * 256;
    int col = ch >> 4;
    int ko = (ch & 15) * 8;
    *(uint4*)(&Bs[col * 136 + ko]) = *(const uint4*)(Bt + col * 128 + ko);
  }
  __syncthreads();
  f32x4 acc[3];
#pragma unroll
  for (int n = 0; n < 3; ++n) acc[n] = (f32x4){0.f, 0.f, 0.f, 0.f};
  const int arow = min(row0 + w * 16 + lr, M - 1);
  const u16* ap = Ab + (size_t)arow * 128 + lk * 8;
#pragma unroll
  for (int kt = 0; kt < 4; ++kt) {
    bf16x8 af = *(const bf16x8*)(ap + kt * 32);
#pragma unroll
    for (int n = 0; n < 3; ++n) {
      bf16x8 bf = *(const bf16x8*)(&Bs[(n * 16 + lr) * 136 + kt * 32 + lk * 8]);
      acc[n] = __builtin_amdgcn_mfma_f32_16x16x32_bf16(af, bf, acc[n], 0, 0, 0);
    }
  }
  const int orow = row0 + w * 16 + (l >> 4) * 4;
#pragma unroll
  for (int n = 0; n < 3; ++n) {
    int c = n * 16 + lr;
    if (c < 40) {
#pragma unroll
      for (int i = 0; i < 4; ++i) {
        int r = orow + i;
        if (r < M) Cb[(size_t)r * 40 + c] = f2b(acc[n][i]);
      }
    }
  }
}

// ---------------- gather layer 2: 40-lane groups, 6 nodes/block, 8-edge unroll ----------------
__global__ __launch_bounds__(256) void gather2_kernel(
    const int* __restrict__ rowstart, const int2* __restrict__ csr,
    const float* __restrict__ dinv,
    const u16* __restrict__ hb, const float* __restrict__ bias,
    float* __restrict__ out, int n) {
  int tid = threadIdx.x;
  if (tid >= 240) return;
  int g = tid / 40;
  int lane = tid - g * 40;
  int w = blockIdx.x * 6 + g;
  if (w >= n) return;
  int beg = rowstart[w], end = rowstart[w + 1];
  float acc0 = 0.f, acc1 = 0.f, acc2 = 0.f, acc3 = 0.f;
  float acc4 = 0.f, acc5 = 0.f, acc6 = 0.f, acc7 = 0.f;
  for (int e0 = beg; e0 < end; e0 += 8) {
    int2 t0 = csr[e0];
    int2 t1 = csr[min(e0 + 1, end - 1)];
    int2 t2 = csr[min(e0 + 2, end - 1)];
    int2 t3 = csr[min(e0 + 3, end - 1)];
    int2 t4 = csr[min(e0 + 4, end - 1)];
    int2 t5 = csr[min(e0 + 5, end - 1)];
    int2 t6 = csr[min(e0 + 6, end - 1)];
    int2 t7 = csr[min(e0 + 7, end - 1)];
    float n0 = __builtin_bit_cast(float, t0.y);
    float n1 = (e0 + 1 < end) ? __builtin_bit_cast(float, t1.y) : 0.f;
    float n2 = (e0 + 2 < end) ? __builtin_bit_cast(float, t2.y) : 0.f;
    float n3 = (e0 + 3 < end) ? __builtin_bit_cast(float, t3.y) : 0.f;
    float n4 = (e0 + 4 < end) ? __builtin_bit_cast(float, t4.y) : 0.f;
    float n5 = (e0 + 5 < end) ? __builtin_bit_cast(float, t5.y) : 0.f;
    float n6 = (e0 + 6 < end) ? __builtin_bit_cast(float, t6.y) : 0.f;
    float n7 = (e0 + 7 < end) ? __builtin_bit_cast(float, t7.y) : 0.f;
    float v0 = b2f(hb[(size_t)t0.x * 40 + lane]);
    float v1 = b2f(hb[(size_t)t1.x * 40 + lane]);
    float v2 = b2f(hb[(size_t)t2.x * 40 + lane]);
    float v3 = b2f(hb[(size_t)t3.x * 40 + lane]);
    float v4 = b2f(hb[(size_t)t4.x * 40 + lane]);
    float v5 = b2f(hb[(size_t)t5.x * 40 + lane]);
    float v6 = b2f(hb[(size_t)t6.x * 40 + lane]);
    float v7 = b2f(hb[(size_t)t7.x * 40 + lane]);
    acc0 += v0 * n0;
    acc1 += v1 * n1;
    acc2 += v2 * n2;
    acc3 += v3 * n3;
    acc4 += v4 * n4;
    acc5 += v5 * n5;
    acc6 += v6 * n6;
    acc7 += v7 * n7;
  }
  float acc = ((acc0 + acc1) + (acc2 + acc3)) + ((acc4 + acc5) + (acc6 + acc7));
  float di = dinv[w];
  out[(size_t)w * 40 + lane] =
      acc + b2f(hb[(size_t)w * 40 + lane]) * di * di + bias[lane];
}

extern "C" void kernel_launch(void* const* d_in, const int* in_sizes, int n_in,
                              void* d_out, int out_size, void* d_ws, size_t ws_size,
                              hipStream_t stream) {
  const float* x  = (const float*)d_in[0];
  const int*  ei  = (const int*)d_in[1];
  const float* W1 = (const float*)d_in[2];
  const float* b1 = (const float*)d_in[3];
  const float* W2 = (const float*)d_in[4];
  const float* b2 = (const float*)d_in[5];
  const int* src = ei;
  const int* dst = ei + N_EDGES;
  float* out = (float*)d_out;

  char* ws = (char*)d_ws;
  int*   degcnt   = (int*)(ws);                 // 100096 ints
  float* dinv     = (float*)(ws + 400384);      // 100096 f32
  int*   rowstart = (int*)(ws + 800768);        // 100352 ints
  int*   bsum     = (int*)(ws + 1202176);       // 256 ints
  int2*  csr      = (int2*)(ws + 1203200);      // 1.6M int2 = 12.8 MB -> ends 14003200
  u16*   w1t      = (u16*)(ws + 14003200);      // 65536 B
  u16*   w2t      = (u16*)(ws + 14068736);      // 12288 B
  u16*   h1b      = (u16*)(ws + 14081024);      // N*128 bf16 = 25.6 MB
  u16*   agg1b    = (u16*)(ws + 39681024);      // N*128 bf16 = 25.6 MB
  u16*   h2b      = (u16*)(ws + 65281024);      // N*40 bf16 = 8 MB
  int*   rank     = (int*)(ws + 65281024);      // 6.4 MB, ALIASES h2b slot
  // (rank used only before gemm2 writes h2b — disjoint in time)

  // --- weight precasts (independent) ---
  cast_w1_kernel<<<128, 256, 0, stream>>>(W1, w1t);
  cast_w2_kernel<<<24, 256, 0, stream>>>(W2, w2t);

  // --- CSR build: single atomic pass ---
  hipMemsetAsync(degcnt, 0, N_NODES * sizeof(int), stream);
  hist_rank_kernel<<<2048, 256, 0, stream>>>(dst, degcnt, rank, N_EDGES);
  dinv_kernel<<<(N_NODES + 255) / 256, 256, 0, stream>>>(degcnt, dinv, N_NODES);
  scan1_kernel<<<196, 256, 0, stream>>>(degcnt, rowstart, bsum, N_NODES);
  scan2_kernel<<<1, 256, 0, stream>>>(bsum, 196);
  scan3_kernel<<<(N_NODES + 255) / 256, 256, 0, stream>>>(rowstart, bsum, N_NODES);
  scatter_fill_kernel<<<2048, 256, 0, stream>>>(src, dst, rank, dinv, rowstart, csr, N_EDGES);

  // --- layer 1 ---
  gemm1_kernel<<<(N_NODES + 63) / 64, 256, 0, stream>>>(x, w1t, h1b, N_NODES);
  gather1_kernel<<<25000, 256, 0, stream>>>(rowstart, csr, dinv, h1b, b1, agg1b, N_NODES);

  // --- layer 2 ---
  gemm2_kernel<<<(N_NODES + 63) / 64, 256, 0, stream>>>(agg1b, w2t, h2b, N_NODES);
  gather2_kernel<<<(N_NODES + 5) / 6, 256, 0, stream>>>(rowstart, csr, dinv, h2b, b2, out, N_NODES);
}